// Round 5
// baseline (463.690 us; speedup 1.0000x reference)
//
#include <hip/hip_runtime.h>
#include <hip/hip_bf16.h>

static constexpr int NN = 50000;
static constexpr int NE = 800000;
static constexpr float BN_EPS = 1e-5f;

__device__ __forceinline__ float bflo(unsigned u) { return __uint_as_float(u << 16); }
__device__ __forceinline__ float bfhi(unsigned u) { return __uint_as_float(u & 0xffff0000u); }
__device__ __forceinline__ unsigned short f2bf(float f) {
    unsigned u = __float_as_uint(f);
    unsigned r = (u + 0x7fffu + ((u >> 16) & 1u)) >> 16;
    return (unsigned short)r;
}

// ===========================================================================
// CSR build
// ===========================================================================
__global__ __launch_bounds__(256) void deg_kernel(const int* __restrict__ dst,
                                                  int* __restrict__ deg)
{
    int e = blockIdx.x * 256 + threadIdx.x;
    if (e < NE) atomicAdd(&deg[dst[e]], 1);
}

__global__ __launch_bounds__(1024) void scan1_kernel(const int* __restrict__ deg,
                                                     int* __restrict__ off,
                                                     int* __restrict__ bsum)
{
    __shared__ int s[1024];
    int t = threadIdx.x;
    int i = blockIdx.x * 1024 + t;
    s[t] = (i < NN) ? deg[i] : 0;
    __syncthreads();
    for (int d = 1; d < 1024; d <<= 1) {
        int x = (t >= d) ? s[t - d] : 0;
        __syncthreads();
        s[t] += x;
        __syncthreads();
    }
    if (i < NN) off[i + 1] = s[t];
    if (t == 1023) bsum[blockIdx.x] = s[1023];
}

__global__ void scan2_kernel(int* bsum, int nblk)
{
    if (threadIdx.x == 0 && blockIdx.x == 0) {
        int run = 0;
        for (int i = 0; i < nblk; ++i) { int v = bsum[i]; bsum[i] = run; run += v; }
    }
}

__global__ __launch_bounds__(256) void scan3_kernel(int* __restrict__ off,
                                                    const int* __restrict__ bsum)
{
    int i = blockIdx.x * 256 + threadIdx.x;
    if (i == 0) off[0] = 0;
    if (i < NN) off[i + 1] += bsum[i >> 10];
}

__global__ __launch_bounds__(256) void fill_kernel(const int* __restrict__ src,
                                                   const int* __restrict__ dst,
                                                   int* __restrict__ cursor,
                                                   int* __restrict__ eidx)
{
    int e = blockIdx.x * 256 + threadIdx.x;
    if (e >= NE) return;
    int pos = atomicAdd(&cursor[dst[e]], 1);
    eidx[pos] = src[e];
}

// ===========================================================================
// proj: p(bf16) = act(hin) @ W1.  act = identity or BN(scale/shift)+relu,
// scale/shift computed in-block from gsum/gsq.  128 rows/block, tile 4x8.
// ===========================================================================
template<int D, bool NORM>
__global__ __launch_bounds__(256) void proj_kernel(
    const float* __restrict__ hin, const float* __restrict__ W1,
    const float* __restrict__ gsum, const float* __restrict__ gsq,
    const float* __restrict__ gamma, const float* __restrict__ beta,
    unsigned short* __restrict__ p)
{
    constexpr int RPB = 128;
    __shared__ float XsT[64][132];     // [k][row], pad->conflict-free
    __shared__ float Ws[64][64];
    __shared__ float scs[64], shs[64];

    const int t = threadIdx.x;
    const int rowbase = blockIdx.x * RPB;

    if (NORM) {
        if (t < 64) {
            const float invn = 1.f / (float)NN;
            float mean = gsum[t] * invn;
            float var  = gsq[t] * invn - mean * mean;
            float sc   = gamma[t] * rsqrtf(var + BN_EPS);
            scs[t] = sc;
            shs[t] = beta[t] - mean * sc;
        }
        __syncthreads();
    }

    const int tc = t & 7;        // col group (8 cols)
    const int tr = t >> 3;       // row group (4 rows)
    const int c0 = tc * 8;
    const int r0 = tr * 4;

    float acc[4][8];
    #pragma unroll
    for (int i = 0; i < 4; ++i)
        #pragma unroll
        for (int j = 0; j < 8; ++j) acc[i][j] = 0.f;

    for (int kc = 0; kc < D; kc += 64) {
        if (kc) __syncthreads();
        {
            const float4* wg = reinterpret_cast<const float4*>(W1 + (size_t)kc * 64);
            float4* wl = reinterpret_cast<float4*>(&Ws[0][0]);
            for (int i = t; i < 64 * 16; i += 256) wl[i] = wg[i];
        }
        {
            int rr = t & 15, q = t >> 4;
            for (int i = 0; i < RPB; i += 16) {
                int r = i + rr;
                int gr = rowbase + r;
                float4 v = make_float4(0.f, 0.f, 0.f, 0.f);
                if (gr < NN) {
                    v = reinterpret_cast<const float4*>(hin + (size_t)gr * D + kc)[q];
                    if (NORM) {
                        int c = q * 4;
                        v.x = fmaxf(v.x * scs[c + 0] + shs[c + 0], 0.f);
                        v.y = fmaxf(v.y * scs[c + 1] + shs[c + 1], 0.f);
                        v.z = fmaxf(v.z * scs[c + 2] + shs[c + 2], 0.f);
                        v.w = fmaxf(v.w * scs[c + 3] + shs[c + 3], 0.f);
                    }
                }
                XsT[q * 4 + 0][r] = v.x;
                XsT[q * 4 + 1][r] = v.y;
                XsT[q * 4 + 2][r] = v.z;
                XsT[q * 4 + 3][r] = v.w;
            }
        }
        __syncthreads();

        for (int k = 0; k < 64; ++k) {
            float4 xa = *reinterpret_cast<const float4*>(&XsT[k][r0]);
            float4 wa = *reinterpret_cast<const float4*>(&Ws[k][c0]);
            float4 wb = *reinterpret_cast<const float4*>(&Ws[k][c0 + 4]);
            float x[4] = { xa.x, xa.y, xa.z, xa.w };
            float w[8] = { wa.x, wa.y, wa.z, wa.w, wb.x, wb.y, wb.z, wb.w };
            #pragma unroll
            for (int i = 0; i < 4; ++i)
                #pragma unroll
                for (int j = 0; j < 8; ++j) acc[i][j] += x[i] * w[j];
        }
    }

    #pragma unroll
    for (int i = 0; i < 4; ++i) {
        int gr = rowbase + r0 + i;
        if (gr < NN) {
            uint4 u;
            u.x = (unsigned)f2bf(acc[i][0]) | ((unsigned)f2bf(acc[i][1]) << 16);
            u.y = (unsigned)f2bf(acc[i][2]) | ((unsigned)f2bf(acc[i][3]) << 16);
            u.z = (unsigned)f2bf(acc[i][4]) | ((unsigned)f2bf(acc[i][5]) << 16);
            u.w = (unsigned)f2bf(acc[i][6]) | ((unsigned)f2bf(acc[i][7]) << 16);
            *reinterpret_cast<uint4*>(p + (size_t)gr * 64 + c0) = u;
        }
    }
}

// ===========================================================================
// aggmlp: fused gather + GEMM2 + BN stats.
//   Y_r = relu(p[r] + sum_{j in N(r)} p[j] + b1)  -> staged transposed in LDS
//   z = Y @ W2 + b2, store z, accumulate gsum/gsq.
// 128 rows/block. Gather: thread (q=t>>4, rr=t&15) does rows rr+16i, quad q.
// ===========================================================================
__global__ __launch_bounds__(256) void aggmlp_kernel(
    const unsigned short* __restrict__ p, const int* __restrict__ off,
    const int* __restrict__ eidx, const float* __restrict__ b1,
    const float* __restrict__ W2, const float* __restrict__ b2,
    float* __restrict__ z, float* __restrict__ gsum, float* __restrict__ gsq)
{
    constexpr int RPB = 128;
    __shared__ float XsT[64][132];
    __shared__ float Ws[64][64];
    __shared__ float b2s[64], lsum[64], lsq[64];

    const int t = threadIdx.x;
    const int rowbase = blockIdx.x * RPB;

    if (t < 64) { b2s[t] = b2[t]; lsum[t] = 0.f; lsq[t] = 0.f; }
    {
        const float4* wg = reinterpret_cast<const float4*>(W2);
        float4* wl = reinterpret_cast<float4*>(&Ws[0][0]);
        for (int i = t; i < 64 * 16; i += 256) wl[i] = wg[i];
    }

    // ---- gather phase ----
    {
        const int q = t >> 4;          // channel quad 0..15
        const int rr = t & 15;         // row slot
        const uint2* pb = reinterpret_cast<const uint2*>(p);
        const float4 bb = reinterpret_cast<const float4*>(b1)[q];
        for (int i = 0; i < RPB; i += 16) {
            int r = i + rr;
            int gr = rowbase + r;
            float a0 = 0.f, a1 = 0.f, a2 = 0.f, a3 = 0.f;
            if (gr < NN) {
                uint2 u = pb[gr * 16 + q];
                a0 = bflo(u.x); a1 = bfhi(u.x); a2 = bflo(u.y); a3 = bfhi(u.y);
                int e = off[gr];
                const int end = off[gr + 1];
                for (; e + 4 <= end; e += 4) {
                    int s0 = eidx[e + 0], s1 = eidx[e + 1];
                    int s2 = eidx[e + 2], s3 = eidx[e + 3];
                    uint2 v0 = pb[s0 * 16 + q];
                    uint2 v1 = pb[s1 * 16 + q];
                    uint2 v2 = pb[s2 * 16 + q];
                    uint2 v3 = pb[s3 * 16 + q];
                    a0 += (bflo(v0.x) + bflo(v1.x)) + (bflo(v2.x) + bflo(v3.x));
                    a1 += (bfhi(v0.x) + bfhi(v1.x)) + (bfhi(v2.x) + bfhi(v3.x));
                    a2 += (bflo(v0.y) + bflo(v1.y)) + (bflo(v2.y) + bflo(v3.y));
                    a3 += (bfhi(v0.y) + bfhi(v1.y)) + (bfhi(v2.y) + bfhi(v3.y));
                }
                for (; e < end; ++e) {
                    uint2 v = pb[eidx[e] * 16 + q];
                    a0 += bflo(v.x); a1 += bfhi(v.x);
                    a2 += bflo(v.y); a3 += bfhi(v.y);
                }
                a0 = fmaxf(a0 + bb.x, 0.f);
                a1 = fmaxf(a1 + bb.y, 0.f);
                a2 = fmaxf(a2 + bb.z, 0.f);
                a3 = fmaxf(a3 + bb.w, 0.f);
            }
            XsT[q * 4 + 0][r] = a0;
            XsT[q * 4 + 1][r] = a1;
            XsT[q * 4 + 2][r] = a2;
            XsT[q * 4 + 3][r] = a3;
        }
    }
    __syncthreads();

    // ---- GEMM2 + stats ----
    const int tc = t & 7;
    const int tr = t >> 3;
    const int c0 = tc * 8;
    const int r0 = tr * 4;

    float acc[4][8];
    #pragma unroll
    for (int i = 0; i < 4; ++i)
        #pragma unroll
        for (int j = 0; j < 8; ++j) acc[i][j] = 0.f;

    for (int k = 0; k < 64; ++k) {
        float4 xa = *reinterpret_cast<const float4*>(&XsT[k][r0]);
        float4 wa = *reinterpret_cast<const float4*>(&Ws[k][c0]);
        float4 wb = *reinterpret_cast<const float4*>(&Ws[k][c0 + 4]);
        float x[4] = { xa.x, xa.y, xa.z, xa.w };
        float w[8] = { wa.x, wa.y, wa.z, wa.w, wb.x, wb.y, wb.z, wb.w };
        #pragma unroll
        for (int i = 0; i < 4; ++i)
            #pragma unroll
            for (int j = 0; j < 8; ++j) acc[i][j] += x[i] * w[j];
    }

    float s[8], sq[8];
    #pragma unroll
    for (int j = 0; j < 8; ++j) { s[j] = 0.f; sq[j] = 0.f; }

    #pragma unroll
    for (int i = 0; i < 4; ++i) {
        int gr = rowbase + r0 + i;
        if (gr < NN) {
            float zv[8];
            #pragma unroll
            for (int j = 0; j < 8; ++j) {
                zv[j] = acc[i][j] + b2s[c0 + j];
                s[j] += zv[j];
                sq[j] += zv[j] * zv[j];
            }
            float4 lo = make_float4(zv[0], zv[1], zv[2], zv[3]);
            float4 hi = make_float4(zv[4], zv[5], zv[6], zv[7]);
            *reinterpret_cast<float4*>(z + (size_t)gr * 64 + c0) = lo;
            *reinterpret_cast<float4*>(z + (size_t)gr * 64 + c0 + 4) = hi;
        }
    }

    #pragma unroll
    for (int j = 0; j < 8; ++j) {
        s[j]  += __shfl_xor(s[j], 8);
        s[j]  += __shfl_xor(s[j], 16);
        s[j]  += __shfl_xor(s[j], 32);
        sq[j] += __shfl_xor(sq[j], 8);
        sq[j] += __shfl_xor(sq[j], 16);
        sq[j] += __shfl_xor(sq[j], 32);
    }
    if ((t & 56) == 0) {
        #pragma unroll
        for (int j = 0; j < 8; ++j) {
            atomicAdd(&lsum[c0 + j], s[j]);
            atomicAdd(&lsq[c0 + j], sq[j]);
        }
    }
    __syncthreads();
    if (t < 64) {
        atomicAdd(&gsum[t], lsum[t]);
        atomicAdd(&gsq[t], lsq[t]);
    }
}

// ===========================================================================
// final norm: out = relu(z*scale+shift), scale/shift computed in-block
// ===========================================================================
__global__ __launch_bounds__(256) void norm_kernel(
    const float* __restrict__ z,
    const float* __restrict__ gsum, const float* __restrict__ gsq,
    const float* __restrict__ gamma, const float* __restrict__ beta,
    float* __restrict__ out)
{
    __shared__ float sc[64], sh[64];
    int t = threadIdx.x;
    if (t < 64) {
        const float invn = 1.f / (float)NN;
        float mean = gsum[t] * invn;
        float var  = gsq[t] * invn - mean * mean;
        float s    = gamma[t] * rsqrtf(var + BN_EPS);
        sc[t] = s;
        sh[t] = beta[t] - mean * s;
    }
    __syncthreads();
    int idx = blockIdx.x * 256 + t;
    if (idx >= NN * 16) return;
    int c = (idx & 15) * 4;
    float4 v = reinterpret_cast<const float4*>(z)[idx];
    v.x = fmaxf(v.x * sc[c + 0] + sh[c + 0], 0.f);
    v.y = fmaxf(v.y * sc[c + 1] + sh[c + 1], 0.f);
    v.z = fmaxf(v.z * sc[c + 2] + sh[c + 2], 0.f);
    v.w = fmaxf(v.w * sc[c + 3] + sh[c + 3], 0.f);
    reinterpret_cast<float4*>(out)[idx] = v;
}

// ===========================================================================
extern "C" void kernel_launch(void* const* d_in, const int* in_sizes, int n_in,
                              void* d_out, int out_size, void* d_ws, size_t ws_size,
                              hipStream_t stream)
{
    const float* h    = (const float*)d_in[0];
    const int*   src  = (const int*)d_in[1];
    const int*   dst  = (const int*)d_in[2];
    const float* W1_0 = (const float*)d_in[3];
    const float* b1_0 = (const float*)d_in[4];
    const float* W2_0 = (const float*)d_in[5];
    const float* b2_0 = (const float*)d_in[6];
    const float* g_0  = (const float*)d_in[7];
    const float* be_0 = (const float*)d_in[8];
    const float* W1st = (const float*)d_in[9];
    const float* b1st = (const float*)d_in[10];
    const float* W2st = (const float*)d_in[11];
    const float* b2st = (const float*)d_in[12];
    const float* gst  = (const float*)d_in[13];
    const float* best = (const float*)d_in[14];
    float* out = (float*)d_out;

    char* ws = (char*)d_ws;
    unsigned short* p = (unsigned short*)ws;                 // NN*64 bf16
    float* stats = (float*)(ws + (size_t)NN * 64 * 2);       // 4 layers x 128
    int* off    = (int*)(stats + 512);                       // NN+1
    int* deg    = off + (NN + 1);
    int* cursor = deg + NN;
    int* bsum   = cursor + NN;
    int* eidx   = bsum + 64;                                 // NE
    float* z    = out;                                       // pre-norm z in d_out

    // ---- CSR build ----
    hipMemsetAsync(deg, 0, NN * sizeof(int), stream);
    deg_kernel<<<(NE + 255) / 256, 256, 0, stream>>>(dst, deg);
    const int nblk = (NN + 1023) / 1024;
    scan1_kernel<<<nblk, 1024, 0, stream>>>(deg, off, bsum);
    scan2_kernel<<<1, 64, 0, stream>>>(bsum, nblk);
    scan3_kernel<<<(NN + 255) / 256, 256, 0, stream>>>(off, bsum);
    hipMemcpyAsync(cursor, off, NN * sizeof(int), hipMemcpyDeviceToDevice, stream);
    fill_kernel<<<(NE + 255) / 256, 256, 0, stream>>>(src, dst, cursor, eidx);
    hipMemsetAsync(stats, 0, 512 * sizeof(float), stream);

    const int gemmblk = (NN + 127) / 128;
    const int thrblk  = (NN * 16 + 255) / 256;

    float* gs0 = stats + 0 * 128;
    proj_kernel<128, false><<<gemmblk, 256, 0, stream>>>(
        h, W1_0, nullptr, nullptr, nullptr, nullptr, p);
    aggmlp_kernel<<<gemmblk, 256, 0, stream>>>(
        p, off, eidx, b1_0, W2_0, b2_0, z, gs0, gs0 + 64);

    const float* gammas[4] = { g_0, gst + 0, gst + 64, gst + 128 };
    const float* betas[4]  = { be_0, best + 0, best + 64, best + 128 };

    for (int l = 0; l < 3; ++l) {
        float* gsp = stats + l * 128;
        float* gsc = stats + (l + 1) * 128;
        proj_kernel<64, true><<<gemmblk, 256, 0, stream>>>(
            z, W1st + l * 4096, gsp, gsp + 64, gammas[l], betas[l], p);
        aggmlp_kernel<<<gemmblk, 256, 0, stream>>>(
            p, off, eidx, b1st + l * 64, W2st + l * 4096, b2st + l * 64,
            z, gsc, gsc + 64);
    }

    float* gs3 = stats + 3 * 128;
    norm_kernel<<<thrblk, 256, 0, stream>>>(z, gs3, gs3 + 64, gammas[3], betas[3], out);
}

// Round 6
// 317.745 us; speedup vs baseline: 1.4593x; 1.4593x over previous
//
#include <hip/hip_runtime.h>
#include <hip/hip_bf16.h>

static constexpr int NN = 50000;
static constexpr int NE = 800000;
static constexpr float BN_EPS = 1e-5f;

__device__ __forceinline__ float bflo(unsigned u) { return __uint_as_float(u << 16); }
__device__ __forceinline__ float bfhi(unsigned u) { return __uint_as_float(u & 0xffff0000u); }
__device__ __forceinline__ unsigned short f2bf(float f) {
    unsigned u = __float_as_uint(f);
    unsigned r = (u + 0x7fffu + ((u >> 16) & 1u)) >> 16;
    return (unsigned short)r;
}

// ===========================================================================
// CSR build
// ===========================================================================
__global__ __launch_bounds__(256) void deg_kernel(const int* __restrict__ dst,
                                                  int* __restrict__ deg)
{
    int e = blockIdx.x * 256 + threadIdx.x;
    if (e < NE) atomicAdd(&deg[dst[e]], 1);
}

__global__ __launch_bounds__(1024) void scan1_kernel(const int* __restrict__ deg,
                                                     int* __restrict__ off,
                                                     int* __restrict__ bsum)
{
    __shared__ int s[1024];
    int t = threadIdx.x;
    int i = blockIdx.x * 1024 + t;
    s[t] = (i < NN) ? deg[i] : 0;
    __syncthreads();
    for (int d = 1; d < 1024; d <<= 1) {
        int x = (t >= d) ? s[t - d] : 0;
        __syncthreads();
        s[t] += x;
        __syncthreads();
    }
    if (i < NN) off[i + 1] = s[t];
    if (t == 1023) bsum[blockIdx.x] = s[1023];
}

__global__ void scan2_kernel(int* bsum, int nblk)
{
    if (threadIdx.x == 0 && blockIdx.x == 0) {
        int run = 0;
        for (int i = 0; i < nblk; ++i) { int v = bsum[i]; bsum[i] = run; run += v; }
    }
}

// also initializes cursor = off (saves a d2d memcpy dispatch)
__global__ __launch_bounds__(256) void scan3_kernel(int* __restrict__ off,
                                                    const int* __restrict__ bsum,
                                                    int* __restrict__ cursor)
{
    int i = blockIdx.x * 256 + threadIdx.x;
    if (i == 0) { off[0] = 0; cursor[0] = 0; }
    if (i < NN) {
        int v = off[i + 1] + bsum[i >> 10];
        off[i + 1] = v;
        if (i + 1 < NN) cursor[i + 1] = v;
    }
}

__global__ __launch_bounds__(256) void fill_kernel(const int* __restrict__ src,
                                                   const int* __restrict__ dst,
                                                   int* __restrict__ cursor,
                                                   int* __restrict__ eidx)
{
    int e = blockIdx.x * 256 + threadIdx.x;
    if (e >= NE) return;
    int pos = atomicAdd(&cursor[dst[e]], 1);
    eidx[pos] = src[e];
}

// ===========================================================================
// proj: p(bf16) = act(hin) @ W1.  act = identity or BN(scale/shift)+relu,
// scale/shift computed in-block from gsum/gsq.  128 rows/block, tile 4x8.
// ===========================================================================
template<int D, bool NORM>
__global__ __launch_bounds__(256) void proj_kernel(
    const float* __restrict__ hin, const float* __restrict__ W1,
    const float* __restrict__ gsum, const float* __restrict__ gsq,
    const float* __restrict__ gamma, const float* __restrict__ beta,
    unsigned short* __restrict__ p)
{
    constexpr int RPB = 128;
    __shared__ float XsT[64][132];     // [k][row], pad->conflict-free
    __shared__ float Ws[64][64];
    __shared__ float scs[64], shs[64];

    const int t = threadIdx.x;
    const int rowbase = blockIdx.x * RPB;

    if (NORM) {
        if (t < 64) {
            const float invn = 1.f / (float)NN;
            float mean = gsum[t] * invn;
            float var  = gsq[t] * invn - mean * mean;
            float sc   = gamma[t] * rsqrtf(var + BN_EPS);
            scs[t] = sc;
            shs[t] = beta[t] - mean * sc;
        }
        __syncthreads();
    }

    const int tc = t & 7;        // col group (8 cols)
    const int tr = t >> 3;       // row group (4 rows)
    const int c0 = tc * 8;
    const int r0 = tr * 4;

    float acc[4][8];
    #pragma unroll
    for (int i = 0; i < 4; ++i)
        #pragma unroll
        for (int j = 0; j < 8; ++j) acc[i][j] = 0.f;

    for (int kc = 0; kc < D; kc += 64) {
        if (kc) __syncthreads();
        {
            const float4* wg = reinterpret_cast<const float4*>(W1 + (size_t)kc * 64);
            float4* wl = reinterpret_cast<float4*>(&Ws[0][0]);
            for (int i = t; i < 64 * 16; i += 256) wl[i] = wg[i];
        }
        {
            int rr = t & 15, q = t >> 4;
            for (int i = 0; i < RPB; i += 16) {
                int r = i + rr;
                int gr = rowbase + r;
                float4 v = make_float4(0.f, 0.f, 0.f, 0.f);
                if (gr < NN) {
                    v = reinterpret_cast<const float4*>(hin + (size_t)gr * D + kc)[q];
                    if (NORM) {
                        int c = q * 4;
                        v.x = fmaxf(v.x * scs[c + 0] + shs[c + 0], 0.f);
                        v.y = fmaxf(v.y * scs[c + 1] + shs[c + 1], 0.f);
                        v.z = fmaxf(v.z * scs[c + 2] + shs[c + 2], 0.f);
                        v.w = fmaxf(v.w * scs[c + 3] + shs[c + 3], 0.f);
                    }
                }
                XsT[q * 4 + 0][r] = v.x;
                XsT[q * 4 + 1][r] = v.y;
                XsT[q * 4 + 2][r] = v.z;
                XsT[q * 4 + 3][r] = v.w;
            }
        }
        __syncthreads();

        for (int k = 0; k < 64; ++k) {
            float4 xa = *reinterpret_cast<const float4*>(&XsT[k][r0]);
            float4 wa = *reinterpret_cast<const float4*>(&Ws[k][c0]);
            float4 wb = *reinterpret_cast<const float4*>(&Ws[k][c0 + 4]);
            float x[4] = { xa.x, xa.y, xa.z, xa.w };
            float w[8] = { wa.x, wa.y, wa.z, wa.w, wb.x, wb.y, wb.z, wb.w };
            #pragma unroll
            for (int i = 0; i < 4; ++i)
                #pragma unroll
                for (int j = 0; j < 8; ++j) acc[i][j] += x[i] * w[j];
        }
    }

    #pragma unroll
    for (int i = 0; i < 4; ++i) {
        int gr = rowbase + r0 + i;
        if (gr < NN) {
            uint4 u;
            u.x = (unsigned)f2bf(acc[i][0]) | ((unsigned)f2bf(acc[i][1]) << 16);
            u.y = (unsigned)f2bf(acc[i][2]) | ((unsigned)f2bf(acc[i][3]) << 16);
            u.z = (unsigned)f2bf(acc[i][4]) | ((unsigned)f2bf(acc[i][5]) << 16);
            u.w = (unsigned)f2bf(acc[i][6]) | ((unsigned)f2bf(acc[i][7]) << 16);
            *reinterpret_cast<uint4*>(p + (size_t)gr * 64 + c0) = u;
        }
    }
}

// ===========================================================================
// gather: Y[i] = relu(p[i] + sum_{j in N(i)} p[j] + b1)   (bf16 in, bf16 out)
// 8 threads/row, 8 channels (16B bf16) each, edge loop unrolled x4.
// ===========================================================================
__global__ __launch_bounds__(256) void gather_kernel(
    const unsigned short* __restrict__ p, const int* __restrict__ off,
    const int* __restrict__ eidx, const float* __restrict__ b1,
    unsigned short* __restrict__ Y)
{
    int gid = blockIdx.x * 256 + threadIdx.x;
    if (gid >= NN * 8) return;
    int row = gid >> 3;
    int q = gid & 7;            // 8-channel slot

    const uint4* pb = reinterpret_cast<const uint4*>(p);
    uint4 u = pb[row * 8 + q];
    float a0 = bflo(u.x), a1 = bfhi(u.x), a2 = bflo(u.y), a3 = bfhi(u.y);
    float a4 = bflo(u.z), a5 = bfhi(u.z), a6 = bflo(u.w), a7 = bfhi(u.w);

    int e = off[row];
    const int end = off[row + 1];
    for (; e + 4 <= end; e += 4) {
        int s0 = eidx[e + 0], s1 = eidx[e + 1];
        int s2 = eidx[e + 2], s3 = eidx[e + 3];
        uint4 v0 = pb[s0 * 8 + q];
        uint4 v1 = pb[s1 * 8 + q];
        uint4 v2 = pb[s2 * 8 + q];
        uint4 v3 = pb[s3 * 8 + q];
        a0 += (bflo(v0.x) + bflo(v1.x)) + (bflo(v2.x) + bflo(v3.x));
        a1 += (bfhi(v0.x) + bfhi(v1.x)) + (bfhi(v2.x) + bfhi(v3.x));
        a2 += (bflo(v0.y) + bflo(v1.y)) + (bflo(v2.y) + bflo(v3.y));
        a3 += (bfhi(v0.y) + bfhi(v1.y)) + (bfhi(v2.y) + bfhi(v3.y));
        a4 += (bflo(v0.z) + bflo(v1.z)) + (bflo(v2.z) + bflo(v3.z));
        a5 += (bfhi(v0.z) + bfhi(v1.z)) + (bfhi(v2.z) + bfhi(v3.z));
        a6 += (bflo(v0.w) + bflo(v1.w)) + (bflo(v2.w) + bflo(v3.w));
        a7 += (bfhi(v0.w) + bfhi(v1.w)) + (bfhi(v2.w) + bfhi(v3.w));
    }
    for (; e < end; ++e) {
        uint4 v = pb[eidx[e] * 8 + q];
        a0 += bflo(v.x); a1 += bfhi(v.x); a2 += bflo(v.y); a3 += bfhi(v.y);
        a4 += bflo(v.z); a5 += bfhi(v.z); a6 += bflo(v.w); a7 += bfhi(v.w);
    }

    float4 blo = reinterpret_cast<const float4*>(b1)[q * 2];
    float4 bhi = reinterpret_cast<const float4*>(b1)[q * 2 + 1];
    a0 = fmaxf(a0 + blo.x, 0.f); a1 = fmaxf(a1 + blo.y, 0.f);
    a2 = fmaxf(a2 + blo.z, 0.f); a3 = fmaxf(a3 + blo.w, 0.f);
    a4 = fmaxf(a4 + bhi.x, 0.f); a5 = fmaxf(a5 + bhi.y, 0.f);
    a6 = fmaxf(a6 + bhi.z, 0.f); a7 = fmaxf(a7 + bhi.w, 0.f);

    uint4 o;
    o.x = (unsigned)f2bf(a0) | ((unsigned)f2bf(a1) << 16);
    o.y = (unsigned)f2bf(a2) | ((unsigned)f2bf(a3) << 16);
    o.z = (unsigned)f2bf(a4) | ((unsigned)f2bf(a5) << 16);
    o.w = (unsigned)f2bf(a6) | ((unsigned)f2bf(a7) << 16);
    reinterpret_cast<uint4*>(Y)[row * 8 + q] = o;
}

// ===========================================================================
// mlp2: z = Y @ W2 + b2 (Y bf16 -> fp32 math), store z fp32, BN stats.
// 128-row block, 4x8 register tile.
// ===========================================================================
__global__ __launch_bounds__(256) void mlp2_kernel(
    const unsigned short* __restrict__ Y, const float* __restrict__ W2,
    const float* __restrict__ b2, float* __restrict__ z,
    float* __restrict__ gsum, float* __restrict__ gsq)
{
    constexpr int RPB = 128;
    __shared__ float XsT[64][132];
    __shared__ float Ws[64][64];
    __shared__ float b2s[64], lsum[64], lsq[64];

    const int t = threadIdx.x;
    const int rowbase = blockIdx.x * RPB;

    if (t < 64) { b2s[t] = b2[t]; lsum[t] = 0.f; lsq[t] = 0.f; }

    {
        const float4* wg = reinterpret_cast<const float4*>(W2);
        float4* wl = reinterpret_cast<float4*>(&Ws[0][0]);
        for (int i = t; i < 64 * 16; i += 256) wl[i] = wg[i];
    }
    {
        const uint4* yb = reinterpret_cast<const uint4*>(Y);
        int rr = t & 31, qq = t >> 5;      // qq 0..7 (8-channel slot)
        for (int i = 0; i < RPB; i += 32) {
            int r = i + rr;
            int gr = rowbase + r;
            uint4 v = make_uint4(0u, 0u, 0u, 0u);
            if (gr < NN) v = yb[gr * 8 + qq];
            int c = qq * 8;
            XsT[c + 0][r] = bflo(v.x); XsT[c + 1][r] = bfhi(v.x);
            XsT[c + 2][r] = bflo(v.y); XsT[c + 3][r] = bfhi(v.y);
            XsT[c + 4][r] = bflo(v.z); XsT[c + 5][r] = bfhi(v.z);
            XsT[c + 6][r] = bflo(v.w); XsT[c + 7][r] = bfhi(v.w);
        }
    }
    __syncthreads();

    const int tc = t & 7;
    const int tr = t >> 3;
    const int c0 = tc * 8;
    const int r0 = tr * 4;

    float acc[4][8];
    #pragma unroll
    for (int i = 0; i < 4; ++i)
        #pragma unroll
        for (int j = 0; j < 8; ++j) acc[i][j] = 0.f;

    for (int k = 0; k < 64; ++k) {
        float4 xa = *reinterpret_cast<const float4*>(&XsT[k][r0]);
        float4 wa = *reinterpret_cast<const float4*>(&Ws[k][c0]);
        float4 wb = *reinterpret_cast<const float4*>(&Ws[k][c0 + 4]);
        float x[4] = { xa.x, xa.y, xa.z, xa.w };
        float w[8] = { wa.x, wa.y, wa.z, wa.w, wb.x, wb.y, wb.z, wb.w };
        #pragma unroll
        for (int i = 0; i < 4; ++i)
            #pragma unroll
            for (int j = 0; j < 8; ++j) acc[i][j] += x[i] * w[j];
    }

    float s[8], sq[8];
    #pragma unroll
    for (int j = 0; j < 8; ++j) { s[j] = 0.f; sq[j] = 0.f; }

    #pragma unroll
    for (int i = 0; i < 4; ++i) {
        int gr = rowbase + r0 + i;
        if (gr < NN) {
            float zv[8];
            #pragma unroll
            for (int j = 0; j < 8; ++j) {
                zv[j] = acc[i][j] + b2s[c0 + j];
                s[j] += zv[j];
                sq[j] += zv[j] * zv[j];
            }
            float4 lo = make_float4(zv[0], zv[1], zv[2], zv[3]);
            float4 hi = make_float4(zv[4], zv[5], zv[6], zv[7]);
            *reinterpret_cast<float4*>(z + (size_t)gr * 64 + c0) = lo;
            *reinterpret_cast<float4*>(z + (size_t)gr * 64 + c0 + 4) = hi;
        }
    }

    #pragma unroll
    for (int j = 0; j < 8; ++j) {
        s[j]  += __shfl_xor(s[j], 8);
        s[j]  += __shfl_xor(s[j], 16);
        s[j]  += __shfl_xor(s[j], 32);
        sq[j] += __shfl_xor(sq[j], 8);
        sq[j] += __shfl_xor(sq[j], 16);
        sq[j] += __shfl_xor(sq[j], 32);
    }
    if ((t & 56) == 0) {
        #pragma unroll
        for (int j = 0; j < 8; ++j) {
            atomicAdd(&lsum[c0 + j], s[j]);
            atomicAdd(&lsq[c0 + j], sq[j]);
        }
    }
    __syncthreads();
    if (t < 64) {
        atomicAdd(&gsum[t], lsum[t]);
        atomicAdd(&gsq[t], lsq[t]);
    }
}

// ===========================================================================
// final norm: out = relu(z*scale+shift), scale/shift computed in-block
// ===========================================================================
__global__ __launch_bounds__(256) void norm_kernel(
    const float* __restrict__ z,
    const float* __restrict__ gsum, const float* __restrict__ gsq,
    const float* __restrict__ gamma, const float* __restrict__ beta,
    float* __restrict__ out)
{
    __shared__ float sc[64], sh[64];
    int t = threadIdx.x;
    if (t < 64) {
        const float invn = 1.f / (float)NN;
        float mean = gsum[t] * invn;
        float var  = gsq[t] * invn - mean * mean;
        float s    = gamma[t] * rsqrtf(var + BN_EPS);
        sc[t] = s;
        sh[t] = beta[t] - mean * s;
    }
    __syncthreads();
    int idx = blockIdx.x * 256 + t;
    if (idx >= NN * 16) return;
    int c = (idx & 15) * 4;
    float4 v = reinterpret_cast<const float4*>(z)[idx];
    v.x = fmaxf(v.x * sc[c + 0] + sh[c + 0], 0.f);
    v.y = fmaxf(v.y * sc[c + 1] + sh[c + 1], 0.f);
    v.z = fmaxf(v.z * sc[c + 2] + sh[c + 2], 0.f);
    v.w = fmaxf(v.w * sc[c + 3] + sh[c + 3], 0.f);
    reinterpret_cast<float4*>(out)[idx] = v;
}

// ===========================================================================
extern "C" void kernel_launch(void* const* d_in, const int* in_sizes, int n_in,
                              void* d_out, int out_size, void* d_ws, size_t ws_size,
                              hipStream_t stream)
{
    const float* h    = (const float*)d_in[0];
    const int*   src  = (const int*)d_in[1];
    const int*   dst  = (const int*)d_in[2];
    const float* W1_0 = (const float*)d_in[3];
    const float* b1_0 = (const float*)d_in[4];
    const float* W2_0 = (const float*)d_in[5];
    const float* b2_0 = (const float*)d_in[6];
    const float* g_0  = (const float*)d_in[7];
    const float* be_0 = (const float*)d_in[8];
    const float* W1st = (const float*)d_in[9];
    const float* b1st = (const float*)d_in[10];
    const float* W2st = (const float*)d_in[11];
    const float* b2st = (const float*)d_in[12];
    const float* gst  = (const float*)d_in[13];
    const float* best = (const float*)d_in[14];
    float* out = (float*)d_out;

    char* ws = (char*)d_ws;
    unsigned short* p = (unsigned short*)ws;                 // NN*64 bf16
    unsigned short* Y = p + (size_t)NN * 64;                 // NN*64 bf16
    float* stats = (float*)(Y + (size_t)NN * 64);            // 512 floats
    int* deg    = (int*)(stats + 512);                       // NN  (adjacent: one memset)
    int* off    = deg + NN;                                  // NN+1
    int* cursor = off + (NN + 1);                            // NN
    int* bsum   = cursor + NN;                               // 64
    int* eidx   = bsum + 64;                                 // NE
    float* z    = out;                                       // pre-norm z in d_out

    // ---- CSR build + stats zero (one memset covers stats+deg) ----
    hipMemsetAsync(stats, 0, (512 + NN) * sizeof(float), stream);
    deg_kernel<<<(NE + 255) / 256, 256, 0, stream>>>(dst, deg);
    const int nblk = (NN + 1023) / 1024;
    scan1_kernel<<<nblk, 1024, 0, stream>>>(deg, off, bsum);
    scan2_kernel<<<1, 64, 0, stream>>>(bsum, nblk);
    scan3_kernel<<<(NN + 255) / 256, 256, 0, stream>>>(off, bsum, cursor);
    fill_kernel<<<(NE + 255) / 256, 256, 0, stream>>>(src, dst, cursor, eidx);

    const int gemmblk   = (NN + 127) / 128;
    const int gatherblk = (NN * 8 + 255) / 256;
    const int thrblk    = (NN * 16 + 255) / 256;

    float* gs0 = stats + 0 * 128;
    proj_kernel<128, false><<<gemmblk, 256, 0, stream>>>(
        h, W1_0, nullptr, nullptr, nullptr, nullptr, p);
    gather_kernel<<<gatherblk, 256, 0, stream>>>(p, off, eidx, b1_0, Y);
    mlp2_kernel<<<gemmblk, 256, 0, stream>>>(Y, W2_0, b2_0, z, gs0, gs0 + 64);

    const float* gammas[4] = { g_0, gst + 0, gst + 64, gst + 128 };
    const float* betas[4]  = { be_0, best + 0, best + 64, best + 128 };

    for (int l = 0; l < 3; ++l) {
        float* gsp = stats + l * 128;
        float* gsc = stats + (l + 1) * 128;
        proj_kernel<64, true><<<gemmblk, 256, 0, stream>>>(
            z, W1st + l * 4096, gsp, gsp + 64, gammas[l], betas[l], p);
        gather_kernel<<<gatherblk, 256, 0, stream>>>(p, off, eidx, b1st + l * 64, Y);
        mlp2_kernel<<<gemmblk, 256, 0, stream>>>(
            Y, W2st + l * 4096, b2st + l * 64, z, gsc, gsc + 64);
    }

    float* gs3 = stats + 3 * 128;
    norm_kernel<<<thrblk, 256, 0, stream>>>(z, gs3, gs3 + 64, gammas[3], betas[3], out);
}

// Round 7
// 302.570 us; speedup vs baseline: 1.5325x; 1.0502x over previous
//
#include <hip/hip_runtime.h>
#include <hip/hip_bf16.h>

static constexpr int NN = 50000;
static constexpr int NE = 800000;
static constexpr float BN_EPS = 1e-5f;

static constexpr int NB  = 128;   // dst buckets
static constexpr int NPB = 391;   // nodes per bucket (128*391 = 50048 >= NN)
static constexpr int CHUNK = 2048;

__device__ __forceinline__ float bflo(unsigned u) { return __uint_as_float(u << 16); }
__device__ __forceinline__ float bfhi(unsigned u) { return __uint_as_float(u & 0xffff0000u); }
__device__ __forceinline__ unsigned short f2bf(float f) {
    unsigned u = __float_as_uint(f);
    unsigned r = (u + 0x7fffu + ((u >> 16) & 1u)) >> 16;
    return (unsigned short)r;
}

// ===========================================================================
// CSR build
// ===========================================================================
__global__ __launch_bounds__(256) void deg_kernel(const int* __restrict__ dst,
                                                  int* __restrict__ deg)
{
    int e = blockIdx.x * 256 + threadIdx.x;
    if (e < NE) atomicAdd(&deg[dst[e]], 1);
}

__global__ __launch_bounds__(1024) void scan1_kernel(const int* __restrict__ deg,
                                                     int* __restrict__ off,
                                                     int* __restrict__ bsum)
{
    __shared__ int s[1024];
    int t = threadIdx.x;
    int i = blockIdx.x * 1024 + t;
    s[t] = (i < NN) ? deg[i] : 0;
    __syncthreads();
    for (int d = 1; d < 1024; d <<= 1) {
        int x = (t >= d) ? s[t - d] : 0;
        __syncthreads();
        s[t] += x;
        __syncthreads();
    }
    if (i < NN) off[i + 1] = s[t];
    if (t == 1023) bsum[blockIdx.x] = s[1023];
}

__global__ void scan2_kernel(int* bsum, int nblk)
{
    if (threadIdx.x == 0 && blockIdx.x == 0) {
        int run = 0;
        for (int i = 0; i < nblk; ++i) { int v = bsum[i]; bsum[i] = run; run += v; }
    }
}

__global__ __launch_bounds__(256) void scan3_kernel(int* __restrict__ off,
                                                    const int* __restrict__ bsum)
{
    int i = blockIdx.x * 256 + threadIdx.x;
    if (i == 0) off[0] = 0;
    if (i < NN) off[i + 1] += bsum[i >> 10];
}

// gcursor[b] = off[b * NPB]
__global__ void initg_kernel(const int* __restrict__ off, int* __restrict__ gcursor)
{
    int b = threadIdx.x;
    if (b < NB) gcursor[b] = off[b * NPB];
}

// ===========================================================================
// binA: LDS-bin edges by dst bucket, flush bucket runs to bucket-major tmp.
// One block per 2048-edge chunk.
// ===========================================================================
__global__ __launch_bounds__(256) void binA_kernel(
    const int* __restrict__ src, const int* __restrict__ dst,
    int* __restrict__ gcursor, unsigned long long* __restrict__ tmp)
{
    __shared__ unsigned long long stage[CHUNK];
    __shared__ int hist[NB], base[NB], gpos[NB];

    const int t = threadIdx.x;
    const int cb = blockIdx.x * CHUNK;
    const int total = min(CHUNK, NE - cb);

    if (t < NB) hist[t] = 0;
    __syncthreads();

    int mb[8], mslot[8];
    unsigned long long mv[8];
    #pragma unroll
    for (int k = 0; k < 8; ++k) {
        int e = cb + k * 256 + t;
        mb[k] = -1;
        if (e < NE) {
            int s = src[e];
            int d = dst[e];
            int b = d / NPB;
            mb[k] = b;
            mv[k] = ((unsigned long long)(unsigned)d << 32) | (unsigned)s;
            mslot[k] = atomicAdd(&hist[b], 1);
        }
    }
    __syncthreads();

    // exclusive prefix of hist -> (base - hist); base = inclusive
    if (t < NB) base[t] = hist[t];
    __syncthreads();
    for (int ofs = 1; ofs < NB; ofs <<= 1) {
        int v = (t >= ofs && t < NB) ? base[t - ofs] : 0;
        __syncthreads();
        if (t < NB) base[t] += v;
        __syncthreads();
    }
    if (t < NB && hist[t] > 0) gpos[t] = atomicAdd(&gcursor[t], hist[t]);
    __syncthreads();

    #pragma unroll
    for (int k = 0; k < 8; ++k) {
        if (mb[k] >= 0) {
            int b = mb[k];
            stage[(base[b] - hist[b]) + mslot[k]] = mv[k];
        }
    }
    __syncthreads();

    for (int i = t; i < total; i += 256) {
        unsigned long long v = stage[i];
        int b = (int)(v >> 32) / NPB;
        int pos = gpos[b] + (i - (base[b] - hist[b]));
        tmp[pos] = v;
    }
}

// ===========================================================================
// binB: one block per bucket; place src into eidx via LDS per-node cursors.
// ===========================================================================
__global__ __launch_bounds__(256) void binB_kernel(
    const unsigned long long* __restrict__ tmp, const int* __restrict__ off,
    int* __restrict__ eidx)
{
    __shared__ int cur[NPB];
    const int t = threadIdx.x;
    const int b = blockIdx.x;
    const int n0 = b * NPB;
    const int n1 = min(n0 + NPB, NN);
    const int cnt = n1 - n0;

    for (int n = t; n < cnt; n += 256) cur[n] = off[n0 + n];
    __syncthreads();

    const int beg = off[n0];
    const int end = off[n1];
    for (int i = beg + t; i < end; i += 256) {
        unsigned long long v = tmp[i];
        int d = (int)(v >> 32);
        int pos = atomicAdd(&cur[d - n0], 1);
        eidx[pos] = (int)(v & 0xffffffffu);
    }
}

// ===========================================================================
// proj: p(bf16) = act(hin) @ W1.  act = identity or BN(scale/shift)+relu.
// 128 rows/block, tile 4x8.
// ===========================================================================
template<int D, bool NORM>
__global__ __launch_bounds__(256) void proj_kernel(
    const float* __restrict__ hin, const float* __restrict__ W1,
    const float* __restrict__ gsum, const float* __restrict__ gsq,
    const float* __restrict__ gamma, const float* __restrict__ beta,
    unsigned short* __restrict__ p)
{
    constexpr int RPB = 128;
    __shared__ float XsT[64][132];
    __shared__ float Ws[64][64];
    __shared__ float scs[64], shs[64];

    const int t = threadIdx.x;
    const int rowbase = blockIdx.x * RPB;

    if (NORM) {
        if (t < 64) {
            const float invn = 1.f / (float)NN;
            float mean = gsum[t] * invn;
            float var  = gsq[t] * invn - mean * mean;
            float sc   = gamma[t] * rsqrtf(var + BN_EPS);
            scs[t] = sc;
            shs[t] = beta[t] - mean * sc;
        }
        __syncthreads();
    }

    const int tc = t & 7;
    const int tr = t >> 3;
    const int c0 = tc * 8;
    const int r0 = tr * 4;

    float acc[4][8];
    #pragma unroll
    for (int i = 0; i < 4; ++i)
        #pragma unroll
        for (int j = 0; j < 8; ++j) acc[i][j] = 0.f;

    for (int kc = 0; kc < D; kc += 64) {
        if (kc) __syncthreads();
        {
            const float4* wg = reinterpret_cast<const float4*>(W1 + (size_t)kc * 64);
            float4* wl = reinterpret_cast<float4*>(&Ws[0][0]);
            for (int i = t; i < 64 * 16; i += 256) wl[i] = wg[i];
        }
        {
            int rr = t & 15, q = t >> 4;
            for (int i = 0; i < RPB; i += 16) {
                int r = i + rr;
                int gr = rowbase + r;
                float4 v = make_float4(0.f, 0.f, 0.f, 0.f);
                if (gr < NN) {
                    v = reinterpret_cast<const float4*>(hin + (size_t)gr * D + kc)[q];
                    if (NORM) {
                        int c = q * 4;
                        v.x = fmaxf(v.x * scs[c + 0] + shs[c + 0], 0.f);
                        v.y = fmaxf(v.y * scs[c + 1] + shs[c + 1], 0.f);
                        v.z = fmaxf(v.z * scs[c + 2] + shs[c + 2], 0.f);
                        v.w = fmaxf(v.w * scs[c + 3] + shs[c + 3], 0.f);
                    }
                }
                XsT[q * 4 + 0][r] = v.x;
                XsT[q * 4 + 1][r] = v.y;
                XsT[q * 4 + 2][r] = v.z;
                XsT[q * 4 + 3][r] = v.w;
            }
        }
        __syncthreads();

        for (int k = 0; k < 64; ++k) {
            float4 xa = *reinterpret_cast<const float4*>(&XsT[k][r0]);
            float4 wa = *reinterpret_cast<const float4*>(&Ws[k][c0]);
            float4 wb = *reinterpret_cast<const float4*>(&Ws[k][c0 + 4]);
            float x[4] = { xa.x, xa.y, xa.z, xa.w };
            float w[8] = { wa.x, wa.y, wa.z, wa.w, wb.x, wb.y, wb.z, wb.w };
            #pragma unroll
            for (int i = 0; i < 4; ++i)
                #pragma unroll
                for (int j = 0; j < 8; ++j) acc[i][j] += x[i] * w[j];
        }
    }

    #pragma unroll
    for (int i = 0; i < 4; ++i) {
        int gr = rowbase + r0 + i;
        if (gr < NN) {
            uint4 u;
            u.x = (unsigned)f2bf(acc[i][0]) | ((unsigned)f2bf(acc[i][1]) << 16);
            u.y = (unsigned)f2bf(acc[i][2]) | ((unsigned)f2bf(acc[i][3]) << 16);
            u.z = (unsigned)f2bf(acc[i][4]) | ((unsigned)f2bf(acc[i][5]) << 16);
            u.w = (unsigned)f2bf(acc[i][6]) | ((unsigned)f2bf(acc[i][7]) << 16);
            *reinterpret_cast<uint4*>(p + (size_t)gr * 64 + c0) = u;
        }
    }
}

// ===========================================================================
// gather: Y[i] = relu(p[i] + sum_{j in N(i)} p[j] + b1)   (bf16 in/out)
// 8 threads/row, 8 channels (16B) each, edge loop unrolled x4.
// ===========================================================================
__global__ __launch_bounds__(256) void gather_kernel(
    const unsigned short* __restrict__ p, const int* __restrict__ off,
    const int* __restrict__ eidx, const float* __restrict__ b1,
    unsigned short* __restrict__ Y)
{
    int gid = blockIdx.x * 256 + threadIdx.x;
    if (gid >= NN * 8) return;
    int row = gid >> 3;
    int q = gid & 7;

    const uint4* pb = reinterpret_cast<const uint4*>(p);
    uint4 u = pb[row * 8 + q];
    float a0 = bflo(u.x), a1 = bfhi(u.x), a2 = bflo(u.y), a3 = bfhi(u.y);
    float a4 = bflo(u.z), a5 = bfhi(u.z), a6 = bflo(u.w), a7 = bfhi(u.w);

    int e = off[row];
    const int end = off[row + 1];
    for (; e + 4 <= end; e += 4) {
        int s0 = eidx[e + 0], s1 = eidx[e + 1];
        int s2 = eidx[e + 2], s3 = eidx[e + 3];
        uint4 v0 = pb[s0 * 8 + q];
        uint4 v1 = pb[s1 * 8 + q];
        uint4 v2 = pb[s2 * 8 + q];
        uint4 v3 = pb[s3 * 8 + q];
        a0 += (bflo(v0.x) + bflo(v1.x)) + (bflo(v2.x) + bflo(v3.x));
        a1 += (bfhi(v0.x) + bfhi(v1.x)) + (bfhi(v2.x) + bfhi(v3.x));
        a2 += (bflo(v0.y) + bflo(v1.y)) + (bflo(v2.y) + bflo(v3.y));
        a3 += (bfhi(v0.y) + bfhi(v1.y)) + (bfhi(v2.y) + bfhi(v3.y));
        a4 += (bflo(v0.z) + bflo(v1.z)) + (bflo(v2.z) + bflo(v3.z));
        a5 += (bfhi(v0.z) + bfhi(v1.z)) + (bfhi(v2.z) + bfhi(v3.z));
        a6 += (bflo(v0.w) + bflo(v1.w)) + (bflo(v2.w) + bflo(v3.w));
        a7 += (bfhi(v0.w) + bfhi(v1.w)) + (bfhi(v2.w) + bfhi(v3.w));
    }
    for (; e < end; ++e) {
        uint4 v = pb[eidx[e] * 8 + q];
        a0 += bflo(v.x); a1 += bfhi(v.x); a2 += bflo(v.y); a3 += bfhi(v.y);
        a4 += bflo(v.z); a5 += bfhi(v.z); a6 += bflo(v.w); a7 += bfhi(v.w);
    }

    float4 blo = reinterpret_cast<const float4*>(b1)[q * 2];
    float4 bhi = reinterpret_cast<const float4*>(b1)[q * 2 + 1];
    a0 = fmaxf(a0 + blo.x, 0.f); a1 = fmaxf(a1 + blo.y, 0.f);
    a2 = fmaxf(a2 + blo.z, 0.f); a3 = fmaxf(a3 + blo.w, 0.f);
    a4 = fmaxf(a4 + bhi.x, 0.f); a5 = fmaxf(a5 + bhi.y, 0.f);
    a6 = fmaxf(a6 + bhi.z, 0.f); a7 = fmaxf(a7 + bhi.w, 0.f);

    uint4 o;
    o.x = (unsigned)f2bf(a0) | ((unsigned)f2bf(a1) << 16);
    o.y = (unsigned)f2bf(a2) | ((unsigned)f2bf(a3) << 16);
    o.z = (unsigned)f2bf(a4) | ((unsigned)f2bf(a5) << 16);
    o.w = (unsigned)f2bf(a6) | ((unsigned)f2bf(a7) << 16);
    reinterpret_cast<uint4*>(Y)[row * 8 + q] = o;
}

// ===========================================================================
// mlp2: z = Y @ W2 + b2 (Y bf16 -> fp32 math), store z fp32, BN stats.
// ===========================================================================
__global__ __launch_bounds__(256) void mlp2_kernel(
    const unsigned short* __restrict__ Y, const float* __restrict__ W2,
    const float* __restrict__ b2, float* __restrict__ z,
    float* __restrict__ gsum, float* __restrict__ gsq)
{
    constexpr int RPB = 128;
    __shared__ float XsT[64][132];
    __shared__ float Ws[64][64];
    __shared__ float b2s[64], lsum[64], lsq[64];

    const int t = threadIdx.x;
    const int rowbase = blockIdx.x * RPB;

    if (t < 64) { b2s[t] = b2[t]; lsum[t] = 0.f; lsq[t] = 0.f; }

    {
        const float4* wg = reinterpret_cast<const float4*>(W2);
        float4* wl = reinterpret_cast<float4*>(&Ws[0][0]);
        for (int i = t; i < 64 * 16; i += 256) wl[i] = wg[i];
    }
    {
        const uint4* yb = reinterpret_cast<const uint4*>(Y);
        int rr = t & 31, qq = t >> 5;
        for (int i = 0; i < RPB; i += 32) {
            int r = i + rr;
            int gr = rowbase + r;
            uint4 v = make_uint4(0u, 0u, 0u, 0u);
            if (gr < NN) v = yb[gr * 8 + qq];
            int c = qq * 8;
            XsT[c + 0][r] = bflo(v.x); XsT[c + 1][r] = bfhi(v.x);
            XsT[c + 2][r] = bflo(v.y); XsT[c + 3][r] = bfhi(v.y);
            XsT[c + 4][r] = bflo(v.z); XsT[c + 5][r] = bfhi(v.z);
            XsT[c + 6][r] = bflo(v.w); XsT[c + 7][r] = bfhi(v.w);
        }
    }
    __syncthreads();

    const int tc = t & 7;
    const int tr = t >> 3;
    const int c0 = tc * 8;
    const int r0 = tr * 4;

    float acc[4][8];
    #pragma unroll
    for (int i = 0; i < 4; ++i)
        #pragma unroll
        for (int j = 0; j < 8; ++j) acc[i][j] = 0.f;

    for (int k = 0; k < 64; ++k) {
        float4 xa = *reinterpret_cast<const float4*>(&XsT[k][r0]);
        float4 wa = *reinterpret_cast<const float4*>(&Ws[k][c0]);
        float4 wb = *reinterpret_cast<const float4*>(&Ws[k][c0 + 4]);
        float x[4] = { xa.x, xa.y, xa.z, xa.w };
        float w[8] = { wa.x, wa.y, wa.z, wa.w, wb.x, wb.y, wb.z, wb.w };
        #pragma unroll
        for (int i = 0; i < 4; ++i)
            #pragma unroll
            for (int j = 0; j < 8; ++j) acc[i][j] += x[i] * w[j];
    }

    float s[8], sq[8];
    #pragma unroll
    for (int j = 0; j < 8; ++j) { s[j] = 0.f; sq[j] = 0.f; }

    #pragma unroll
    for (int i = 0; i < 4; ++i) {
        int gr = rowbase + r0 + i;
        if (gr < NN) {
            float zv[8];
            #pragma unroll
            for (int j = 0; j < 8; ++j) {
                zv[j] = acc[i][j] + b2s[c0 + j];
                s[j] += zv[j];
                sq[j] += zv[j] * zv[j];
            }
            float4 lo = make_float4(zv[0], zv[1], zv[2], zv[3]);
            float4 hi = make_float4(zv[4], zv[5], zv[6], zv[7]);
            *reinterpret_cast<float4*>(z + (size_t)gr * 64 + c0) = lo;
            *reinterpret_cast<float4*>(z + (size_t)gr * 64 + c0 + 4) = hi;
        }
    }

    #pragma unroll
    for (int j = 0; j < 8; ++j) {
        s[j]  += __shfl_xor(s[j], 8);
        s[j]  += __shfl_xor(s[j], 16);
        s[j]  += __shfl_xor(s[j], 32);
        sq[j] += __shfl_xor(sq[j], 8);
        sq[j] += __shfl_xor(sq[j], 16);
        sq[j] += __shfl_xor(sq[j], 32);
    }
    if ((t & 56) == 0) {
        #pragma unroll
        for (int j = 0; j < 8; ++j) {
            atomicAdd(&lsum[c0 + j], s[j]);
            atomicAdd(&lsq[c0 + j], sq[j]);
        }
    }
    __syncthreads();
    if (t < 64) {
        atomicAdd(&gsum[t], lsum[t]);
        atomicAdd(&gsq[t], lsq[t]);
    }
}

// ===========================================================================
// final norm: out = relu(z*scale+shift)
// ===========================================================================
__global__ __launch_bounds__(256) void norm_kernel(
    const float* __restrict__ z,
    const float* __restrict__ gsum, const float* __restrict__ gsq,
    const float* __restrict__ gamma, const float* __restrict__ beta,
    float* __restrict__ out)
{
    __shared__ float sc[64], sh[64];
    int t = threadIdx.x;
    if (t < 64) {
        const float invn = 1.f / (float)NN;
        float mean = gsum[t] * invn;
        float var  = gsq[t] * invn - mean * mean;
        float s    = gamma[t] * rsqrtf(var + BN_EPS);
        sc[t] = s;
        sh[t] = beta[t] - mean * s;
    }
    __syncthreads();
    int idx = blockIdx.x * 256 + t;
    if (idx >= NN * 16) return;
    int c = (idx & 15) * 4;
    float4 v = reinterpret_cast<const float4*>(z)[idx];
    v.x = fmaxf(v.x * sc[c + 0] + sh[c + 0], 0.f);
    v.y = fmaxf(v.y * sc[c + 1] + sh[c + 1], 0.f);
    v.z = fmaxf(v.z * sc[c + 2] + sh[c + 2], 0.f);
    v.w = fmaxf(v.w * sc[c + 3] + sh[c + 3], 0.f);
    reinterpret_cast<float4*>(out)[idx] = v;
}

// ===========================================================================
extern "C" void kernel_launch(void* const* d_in, const int* in_sizes, int n_in,
                              void* d_out, int out_size, void* d_ws, size_t ws_size,
                              hipStream_t stream)
{
    const float* h    = (const float*)d_in[0];
    const int*   src  = (const int*)d_in[1];
    const int*   dst  = (const int*)d_in[2];
    const float* W1_0 = (const float*)d_in[3];
    const float* b1_0 = (const float*)d_in[4];
    const float* W2_0 = (const float*)d_in[5];
    const float* b2_0 = (const float*)d_in[6];
    const float* g_0  = (const float*)d_in[7];
    const float* be_0 = (const float*)d_in[8];
    const float* W1st = (const float*)d_in[9];
    const float* b1st = (const float*)d_in[10];
    const float* W2st = (const float*)d_in[11];
    const float* b2st = (const float*)d_in[12];
    const float* gst  = (const float*)d_in[13];
    const float* best = (const float*)d_in[14];
    float* out = (float*)d_out;

    char* ws = (char*)d_ws;
    unsigned short* p = (unsigned short*)ws;                     // NN*64 bf16
    unsigned short* Y = p + (size_t)NN * 64;                     // NN*64 bf16
    unsigned long long* tmp = (unsigned long long*)(Y + (size_t)NN * 64);  // NE u64 (8B aligned)
    int* eidx   = (int*)(tmp + NE);                              // NE
    float* stats = (float*)(eidx + NE);                          // 512
    int* deg    = (int*)(stats + 512);                           // NN (adjacent to stats for one memset)
    int* off    = deg + NN;                                      // NN+1
    int* bsum   = off + (NN + 1);                                // 64
    int* gcursor = bsum + 64;                                    // NB
    float* z    = out;                                           // pre-norm z in d_out

    // ---- CSR build (bucketed two-phase, no cross-XCD write sharing) ----
    hipMemsetAsync(stats, 0, (512 + NN) * sizeof(float), stream);
    deg_kernel<<<(NE + 255) / 256, 256, 0, stream>>>(dst, deg);
    const int nblk = (NN + 1023) / 1024;
    scan1_kernel<<<nblk, 1024, 0, stream>>>(deg, off, bsum);
    scan2_kernel<<<1, 64, 0, stream>>>(bsum, nblk);
    scan3_kernel<<<(NN + 255) / 256, 256, 0, stream>>>(off, bsum);
    initg_kernel<<<1, NB, 0, stream>>>(off, gcursor);
    binA_kernel<<<(NE + CHUNK - 1) / CHUNK, 256, 0, stream>>>(src, dst, gcursor, tmp);
    binB_kernel<<<NB, 256, 0, stream>>>(tmp, off, eidx);

    const int gemmblk   = (NN + 127) / 128;
    const int gatherblk = (NN * 8 + 255) / 256;
    const int thrblk    = (NN * 16 + 255) / 256;

    float* gs0 = stats + 0 * 128;
    proj_kernel<128, false><<<gemmblk, 256, 0, stream>>>(
        h, W1_0, nullptr, nullptr, nullptr, nullptr, p);
    gather_kernel<<<gatherblk, 256, 0, stream>>>(p, off, eidx, b1_0, Y);
    mlp2_kernel<<<gemmblk, 256, 0, stream>>>(Y, W2_0, b2_0, z, gs0, gs0 + 64);

    const float* gammas[4] = { g_0, gst + 0, gst + 64, gst + 128 };
    const float* betas[4]  = { be_0, best + 0, best + 64, best + 128 };

    for (int l = 0; l < 3; ++l) {
        float* gsp = stats + l * 128;
        float* gsc = stats + (l + 1) * 128;
        proj_kernel<64, true><<<gemmblk, 256, 0, stream>>>(
            z, W1st + l * 4096, gsp, gsp + 64, gammas[l], betas[l], p);
        gather_kernel<<<gatherblk, 256, 0, stream>>>(p, off, eidx, b1st + l * 64, Y);
        mlp2_kernel<<<gemmblk, 256, 0, stream>>>(
            Y, W2st + l * 4096, b2st + l * 64, z, gsc, gsc + 64);
    }

    float* gs3 = stats + 3 * 128;
    norm_kernel<<<thrblk, 256, 0, stream>>>(z, gs3, gs3 + 64, gammas[3], betas[3], out);
}

// Round 8
// 301.003 us; speedup vs baseline: 1.5405x; 1.0052x over previous
//
#include <hip/hip_runtime.h>
#include <hip/hip_bf16.h>

static constexpr int NN = 50000;
static constexpr int NE = 800000;
static constexpr float BN_EPS = 1e-5f;

static constexpr int NB  = 128;   // dst buckets
static constexpr int NPB = 391;   // nodes per bucket (128*391 = 50048 >= NN)
static constexpr int CHUNK = 2048;

__device__ __forceinline__ float bflo(unsigned u) { return __uint_as_float(u << 16); }
__device__ __forceinline__ float bfhi(unsigned u) { return __uint_as_float(u & 0xffff0000u); }
__device__ __forceinline__ unsigned short f2bf(float f) {
    unsigned u = __float_as_uint(f);
    unsigned r = (u + 0x7fffu + ((u >> 16) & 1u)) >> 16;
    return (unsigned short)r;
}

// ===========================================================================
// zero: grid-stride int store (replaces slow rocclr fillBuffer for small n)
// ===========================================================================
__global__ __launch_bounds__(256) void zero_kernel(int* __restrict__ ptr, int n)
{
    int i = blockIdx.x * 256 + threadIdx.x;
    if (i < n) ptr[i] = 0;
}

// ===========================================================================
// CSR build
// ===========================================================================
__global__ __launch_bounds__(256) void deg_kernel(const int* __restrict__ dst,
                                                  int* __restrict__ deg)
{
    int e = blockIdx.x * 256 + threadIdx.x;
    if (e < NE) atomicAdd(&deg[dst[e]], 1);
}

__global__ __launch_bounds__(1024) void scan1_kernel(const int* __restrict__ deg,
                                                     int* __restrict__ off,
                                                     int* __restrict__ bsum)
{
    __shared__ int s[1024];
    int t = threadIdx.x;
    int i = blockIdx.x * 1024 + t;
    s[t] = (i < NN) ? deg[i] : 0;
    __syncthreads();
    for (int d = 1; d < 1024; d <<= 1) {
        int x = (t >= d) ? s[t - d] : 0;
        __syncthreads();
        s[t] += x;
        __syncthreads();
    }
    if (i < NN) off[i + 1] = s[t];
    if (t == 1023) bsum[blockIdx.x] = s[1023];
}

__global__ void scan2_kernel(int* bsum, int nblk)
{
    if (threadIdx.x == 0 && blockIdx.x == 0) {
        int run = 0;
        for (int i = 0; i < nblk; ++i) { int v = bsum[i]; bsum[i] = run; run += v; }
    }
}

// also writes gcursor[b] = off[b*NPB] (fused initg)
__global__ __launch_bounds__(256) void scan3_kernel(int* __restrict__ off,
                                                    const int* __restrict__ bsum,
                                                    int* __restrict__ gcursor)
{
    int i = blockIdx.x * 256 + threadIdx.x;
    if (i == 0) { off[0] = 0; gcursor[0] = 0; }
    if (i < NN) {
        int v = off[i + 1] + bsum[i >> 10];
        off[i + 1] = v;
        int n = i + 1;
        if (n % NPB == 0 && n / NPB < NB) gcursor[n / NPB] = v;
    }
}

// ===========================================================================
// binA: LDS-bin edges by dst bucket, flush bucket runs to bucket-major tmp.
// ===========================================================================
__global__ __launch_bounds__(256) void binA_kernel(
    const int* __restrict__ src, const int* __restrict__ dst,
    int* __restrict__ gcursor, unsigned long long* __restrict__ tmp)
{
    __shared__ unsigned long long stage[CHUNK];
    __shared__ int hist[NB], base[NB], gpos[NB];

    const int t = threadIdx.x;
    const int cb = blockIdx.x * CHUNK;
    const int total = min(CHUNK, NE - cb);

    if (t < NB) hist[t] = 0;
    __syncthreads();

    int mb[8], mslot[8];
    unsigned long long mv[8];
    #pragma unroll
    for (int k = 0; k < 8; ++k) {
        int e = cb + k * 256 + t;
        mb[k] = -1;
        if (e < NE) {
            int s = src[e];
            int d = dst[e];
            int b = d / NPB;
            mb[k] = b;
            mv[k] = ((unsigned long long)(unsigned)d << 32) | (unsigned)s;
            mslot[k] = atomicAdd(&hist[b], 1);
        }
    }
    __syncthreads();

    if (t < NB) base[t] = hist[t];
    __syncthreads();
    for (int ofs = 1; ofs < NB; ofs <<= 1) {
        int v = (t >= ofs && t < NB) ? base[t - ofs] : 0;
        __syncthreads();
        if (t < NB) base[t] += v;
        __syncthreads();
    }
    if (t < NB && hist[t] > 0) gpos[t] = atomicAdd(&gcursor[t], hist[t]);
    __syncthreads();

    #pragma unroll
    for (int k = 0; k < 8; ++k) {
        if (mb[k] >= 0) {
            int b = mb[k];
            stage[(base[b] - hist[b]) + mslot[k]] = mv[k];
        }
    }
    __syncthreads();

    for (int i = t; i < total; i += 256) {
        unsigned long long v = stage[i];
        int b = (int)(v >> 32) / NPB;
        int pos = gpos[b] + (i - (base[b] - hist[b]));
        tmp[pos] = v;
    }
}

// ===========================================================================
// binB: one block per bucket; place src into eidx via LDS per-node cursors.
// ===========================================================================
__global__ __launch_bounds__(256) void binB_kernel(
    const unsigned long long* __restrict__ tmp, const int* __restrict__ off,
    int* __restrict__ eidx)
{
    __shared__ int cur[NPB];
    const int t = threadIdx.x;
    const int b = blockIdx.x;
    const int n0 = b * NPB;
    const int n1 = min(n0 + NPB, NN);
    const int cnt = n1 - n0;

    for (int n = t; n < cnt; n += 256) cur[n] = off[n0 + n];
    __syncthreads();

    const int beg = off[n0];
    const int end = off[n1];
    for (int i = beg + t; i < end; i += 256) {
        unsigned long long v = tmp[i];
        int d = (int)(v >> 32);
        int pos = atomicAdd(&cur[d - n0], 1);
        eidx[pos] = (int)(v & 0xffffffffu);
    }
}

// ===========================================================================
// proj: p(bf16) = act(hin) @ W1.  act = identity or BN(scale/shift)+relu.
// 128 rows/block, tile 4x8.
// ===========================================================================
template<int D, bool NORM>
__global__ __launch_bounds__(256) void proj_kernel(
    const float* __restrict__ hin, const float* __restrict__ W1,
    const float* __restrict__ gsum, const float* __restrict__ gsq,
    const float* __restrict__ gamma, const float* __restrict__ beta,
    unsigned short* __restrict__ p)
{
    constexpr int RPB = 128;
    __shared__ float XsT[64][132];
    __shared__ float Ws[64][64];
    __shared__ float scs[64], shs[64];

    const int t = threadIdx.x;
    const int rowbase = blockIdx.x * RPB;

    if (NORM) {
        if (t < 64) {
            const float invn = 1.f / (float)NN;
            float mean = gsum[t] * invn;
            float var  = gsq[t] * invn - mean * mean;
            float sc   = gamma[t] * rsqrtf(var + BN_EPS);
            scs[t] = sc;
            shs[t] = beta[t] - mean * sc;
        }
        __syncthreads();
    }

    const int tc = t & 7;
    const int tr = t >> 3;
    const int c0 = tc * 8;
    const int r0 = tr * 4;

    float acc[4][8];
    #pragma unroll
    for (int i = 0; i < 4; ++i)
        #pragma unroll
        for (int j = 0; j < 8; ++j) acc[i][j] = 0.f;

    for (int kc = 0; kc < D; kc += 64) {
        if (kc) __syncthreads();
        {
            const float4* wg = reinterpret_cast<const float4*>(W1 + (size_t)kc * 64);
            float4* wl = reinterpret_cast<float4*>(&Ws[0][0]);
            for (int i = t; i < 64 * 16; i += 256) wl[i] = wg[i];
        }
        {
            int rr = t & 15, q = t >> 4;
            for (int i = 0; i < RPB; i += 16) {
                int r = i + rr;
                int gr = rowbase + r;
                float4 v = make_float4(0.f, 0.f, 0.f, 0.f);
                if (gr < NN) {
                    v = reinterpret_cast<const float4*>(hin + (size_t)gr * D + kc)[q];
                    if (NORM) {
                        int c = q * 4;
                        v.x = fmaxf(v.x * scs[c + 0] + shs[c + 0], 0.f);
                        v.y = fmaxf(v.y * scs[c + 1] + shs[c + 1], 0.f);
                        v.z = fmaxf(v.z * scs[c + 2] + shs[c + 2], 0.f);
                        v.w = fmaxf(v.w * scs[c + 3] + shs[c + 3], 0.f);
                    }
                }
                XsT[q * 4 + 0][r] = v.x;
                XsT[q * 4 + 1][r] = v.y;
                XsT[q * 4 + 2][r] = v.z;
                XsT[q * 4 + 3][r] = v.w;
            }
        }
        __syncthreads();

        for (int k = 0; k < 64; ++k) {
            float4 xa = *reinterpret_cast<const float4*>(&XsT[k][r0]);
            float4 wa = *reinterpret_cast<const float4*>(&Ws[k][c0]);
            float4 wb = *reinterpret_cast<const float4*>(&Ws[k][c0 + 4]);
            float x[4] = { xa.x, xa.y, xa.z, xa.w };
            float w[8] = { wa.x, wa.y, wa.z, wa.w, wb.x, wb.y, wb.z, wb.w };
            #pragma unroll
            for (int i = 0; i < 4; ++i)
                #pragma unroll
                for (int j = 0; j < 8; ++j) acc[i][j] += x[i] * w[j];
        }
    }

    #pragma unroll
    for (int i = 0; i < 4; ++i) {
        int gr = rowbase + r0 + i;
        if (gr < NN) {
            uint4 u;
            u.x = (unsigned)f2bf(acc[i][0]) | ((unsigned)f2bf(acc[i][1]) << 16);
            u.y = (unsigned)f2bf(acc[i][2]) | ((unsigned)f2bf(acc[i][3]) << 16);
            u.z = (unsigned)f2bf(acc[i][4]) | ((unsigned)f2bf(acc[i][5]) << 16);
            u.w = (unsigned)f2bf(acc[i][6]) | ((unsigned)f2bf(acc[i][7]) << 16);
            *reinterpret_cast<uint4*>(p + (size_t)gr * 64 + c0) = u;
        }
    }
}

// ===========================================================================
// gather: Y[i] = relu(p[i] + sum_{j in N(i)} p[j] + b1)   (bf16 in/out)
// ===========================================================================
__global__ __launch_bounds__(256) void gather_kernel(
    const unsigned short* __restrict__ p, const int* __restrict__ off,
    const int* __restrict__ eidx, const float* __restrict__ b1,
    unsigned short* __restrict__ Y)
{
    int gid = blockIdx.x * 256 + threadIdx.x;
    if (gid >= NN * 8) return;
    int row = gid >> 3;
    int q = gid & 7;

    const uint4* pb = reinterpret_cast<const uint4*>(p);
    uint4 u = pb[row * 8 + q];
    float a0 = bflo(u.x), a1 = bfhi(u.x), a2 = bflo(u.y), a3 = bfhi(u.y);
    float a4 = bflo(u.z), a5 = bfhi(u.z), a6 = bflo(u.w), a7 = bfhi(u.w);

    int e = off[row];
    const int end = off[row + 1];
    for (; e + 4 <= end; e += 4) {
        int s0 = eidx[e + 0], s1 = eidx[e + 1];
        int s2 = eidx[e + 2], s3 = eidx[e + 3];
        uint4 v0 = pb[s0 * 8 + q];
        uint4 v1 = pb[s1 * 8 + q];
        uint4 v2 = pb[s2 * 8 + q];
        uint4 v3 = pb[s3 * 8 + q];
        a0 += (bflo(v0.x) + bflo(v1.x)) + (bflo(v2.x) + bflo(v3.x));
        a1 += (bfhi(v0.x) + bfhi(v1.x)) + (bfhi(v2.x) + bfhi(v3.x));
        a2 += (bflo(v0.y) + bflo(v1.y)) + (bflo(v2.y) + bflo(v3.y));
        a3 += (bfhi(v0.y) + bfhi(v1.y)) + (bfhi(v2.y) + bfhi(v3.y));
        a4 += (bflo(v0.z) + bflo(v1.z)) + (bflo(v2.z) + bflo(v3.z));
        a5 += (bfhi(v0.z) + bfhi(v1.z)) + (bfhi(v2.z) + bfhi(v3.z));
        a6 += (bflo(v0.w) + bflo(v1.w)) + (bflo(v2.w) + bflo(v3.w));
        a7 += (bfhi(v0.w) + bfhi(v1.w)) + (bfhi(v2.w) + bfhi(v3.w));
    }
    for (; e < end; ++e) {
        uint4 v = pb[eidx[e] * 8 + q];
        a0 += bflo(v.x); a1 += bfhi(v.x); a2 += bflo(v.y); a3 += bfhi(v.y);
        a4 += bflo(v.z); a5 += bfhi(v.z); a6 += bflo(v.w); a7 += bfhi(v.w);
    }

    float4 blo = reinterpret_cast<const float4*>(b1)[q * 2];
    float4 bhi = reinterpret_cast<const float4*>(b1)[q * 2 + 1];
    a0 = fmaxf(a0 + blo.x, 0.f); a1 = fmaxf(a1 + blo.y, 0.f);
    a2 = fmaxf(a2 + blo.z, 0.f); a3 = fmaxf(a3 + blo.w, 0.f);
    a4 = fmaxf(a4 + bhi.x, 0.f); a5 = fmaxf(a5 + bhi.y, 0.f);
    a6 = fmaxf(a6 + bhi.z, 0.f); a7 = fmaxf(a7 + bhi.w, 0.f);

    uint4 o;
    o.x = (unsigned)f2bf(a0) | ((unsigned)f2bf(a1) << 16);
    o.y = (unsigned)f2bf(a2) | ((unsigned)f2bf(a3) << 16);
    o.z = (unsigned)f2bf(a4) | ((unsigned)f2bf(a5) << 16);
    o.w = (unsigned)f2bf(a6) | ((unsigned)f2bf(a7) << 16);
    reinterpret_cast<uint4*>(Y)[row * 8 + q] = o;
}

// ===========================================================================
// mlp2: z = Y @ W2 + b2 (Y bf16 -> fp32 math), store z fp32, BN stats.
// ===========================================================================
__global__ __launch_bounds__(256) void mlp2_kernel(
    const unsigned short* __restrict__ Y, const float* __restrict__ W2,
    const float* __restrict__ b2, float* __restrict__ z,
    float* __restrict__ gsum, float* __restrict__ gsq)
{
    constexpr int RPB = 128;
    __shared__ float XsT[64][132];
    __shared__ float Ws[64][64];
    __shared__ float b2s[64], lsum[64], lsq[64];

    const int t = threadIdx.x;
    const int rowbase = blockIdx.x * RPB;

    if (t < 64) { b2s[t] = b2[t]; lsum[t] = 0.f; lsq[t] = 0.f; }

    {
        const float4* wg = reinterpret_cast<const float4*>(W2);
        float4* wl = reinterpret_cast<float4*>(&Ws[0][0]);
        for (int i = t; i < 64 * 16; i += 256) wl[i] = wg[i];
    }
    {
        const uint4* yb = reinterpret_cast<const uint4*>(Y);
        int rr = t & 31, qq = t >> 5;
        for (int i = 0; i < RPB; i += 32) {
            int r = i + rr;
            int gr = rowbase + r;
            uint4 v = make_uint4(0u, 0u, 0u, 0u);
            if (gr < NN) v = yb[gr * 8 + qq];
            int c = qq * 8;
            XsT[c + 0][r] = bflo(v.x); XsT[c + 1][r] = bfhi(v.x);
            XsT[c + 2][r] = bflo(v.y); XsT[c + 3][r] = bfhi(v.y);
            XsT[c + 4][r] = bflo(v.z); XsT[c + 5][r] = bfhi(v.z);
            XsT[c + 6][r] = bflo(v.w); XsT[c + 7][r] = bfhi(v.w);
        }
    }
    __syncthreads();

    const int tc = t & 7;
    const int tr = t >> 3;
    const int c0 = tc * 8;
    const int r0 = tr * 4;

    float acc[4][8];
    #pragma unroll
    for (int i = 0; i < 4; ++i)
        #pragma unroll
        for (int j = 0; j < 8; ++j) acc[i][j] = 0.f;

    for (int k = 0; k < 64; ++k) {
        float4 xa = *reinterpret_cast<const float4*>(&XsT[k][r0]);
        float4 wa = *reinterpret_cast<const float4*>(&Ws[k][c0]);
        float4 wb = *reinterpret_cast<const float4*>(&Ws[k][c0 + 4]);
        float x[4] = { xa.x, xa.y, xa.z, xa.w };
        float w[8] = { wa.x, wa.y, wa.z, wa.w, wb.x, wb.y, wb.z, wb.w };
        #pragma unroll
        for (int i = 0; i < 4; ++i)
            #pragma unroll
            for (int j = 0; j < 8; ++j) acc[i][j] += x[i] * w[j];
    }

    float s[8], sq[8];
    #pragma unroll
    for (int j = 0; j < 8; ++j) { s[j] = 0.f; sq[j] = 0.f; }

    #pragma unroll
    for (int i = 0; i < 4; ++i) {
        int gr = rowbase + r0 + i;
        if (gr < NN) {
            float zv[8];
            #pragma unroll
            for (int j = 0; j < 8; ++j) {
                zv[j] = acc[i][j] + b2s[c0 + j];
                s[j] += zv[j];
                sq[j] += zv[j] * zv[j];
            }
            float4 lo = make_float4(zv[0], zv[1], zv[2], zv[3]);
            float4 hi = make_float4(zv[4], zv[5], zv[6], zv[7]);
            *reinterpret_cast<float4*>(z + (size_t)gr * 64 + c0) = lo;
            *reinterpret_cast<float4*>(z + (size_t)gr * 64 + c0 + 4) = hi;
        }
    }

    #pragma unroll
    for (int j = 0; j < 8; ++j) {
        s[j]  += __shfl_xor(s[j], 8);
        s[j]  += __shfl_xor(s[j], 16);
        s[j]  += __shfl_xor(s[j], 32);
        sq[j] += __shfl_xor(sq[j], 8);
        sq[j] += __shfl_xor(sq[j], 16);
        sq[j] += __shfl_xor(sq[j], 32);
    }
    if ((t & 56) == 0) {
        #pragma unroll
        for (int j = 0; j < 8; ++j) {
            atomicAdd(&lsum[c0 + j], s[j]);
            atomicAdd(&lsq[c0 + j], sq[j]);
        }
    }
    __syncthreads();
    if (t < 64) {
        atomicAdd(&gsum[t], lsum[t]);
        atomicAdd(&gsq[t], lsq[t]);
    }
}

// ===========================================================================
// final norm: out = relu(z*scale+shift)
// ===========================================================================
__global__ __launch_bounds__(256) void norm_kernel(
    const float* __restrict__ z,
    const float* __restrict__ gsum, const float* __restrict__ gsq,
    const float* __restrict__ gamma, const float* __restrict__ beta,
    float* __restrict__ out)
{
    __shared__ float sc[64], sh[64];
    int t = threadIdx.x;
    if (t < 64) {
        const float invn = 1.f / (float)NN;
        float mean = gsum[t] * invn;
        float var  = gsq[t] * invn - mean * mean;
        float s    = gamma[t] * rsqrtf(var + BN_EPS);
        sc[t] = s;
        sh[t] = beta[t] - mean * s;
    }
    __syncthreads();
    int idx = blockIdx.x * 256 + t;
    if (idx >= NN * 16) return;
    int c = (idx & 15) * 4;
    float4 v = reinterpret_cast<const float4*>(z)[idx];
    v.x = fmaxf(v.x * sc[c + 0] + sh[c + 0], 0.f);
    v.y = fmaxf(v.y * sc[c + 1] + sh[c + 1], 0.f);
    v.z = fmaxf(v.z * sc[c + 2] + sh[c + 2], 0.f);
    v.w = fmaxf(v.w * sc[c + 3] + sh[c + 3], 0.f);
    reinterpret_cast<float4*>(out)[idx] = v;
}

// ===========================================================================
extern "C" void kernel_launch(void* const* d_in, const int* in_sizes, int n_in,
                              void* d_out, int out_size, void* d_ws, size_t ws_size,
                              hipStream_t stream)
{
    const float* h    = (const float*)d_in[0];
    const int*   src  = (const int*)d_in[1];
    const int*   dst  = (const int*)d_in[2];
    const float* W1_0 = (const float*)d_in[3];
    const float* b1_0 = (const float*)d_in[4];
    const float* W2_0 = (const float*)d_in[5];
    const float* b2_0 = (const float*)d_in[6];
    const float* g_0  = (const float*)d_in[7];
    const float* be_0 = (const float*)d_in[8];
    const float* W1st = (const float*)d_in[9];
    const float* b1st = (const float*)d_in[10];
    const float* W2st = (const float*)d_in[11];
    const float* b2st = (const float*)d_in[12];
    const float* gst  = (const float*)d_in[13];
    const float* best = (const float*)d_in[14];
    float* out = (float*)d_out;

    char* ws = (char*)d_ws;
    unsigned short* p = (unsigned short*)ws;                     // NN*64 bf16
    unsigned short* Y = p + (size_t)NN * 64;                     // NN*64 bf16
    unsigned long long* tmp = (unsigned long long*)(Y + (size_t)NN * 64);  // NE u64
    int* eidx   = (int*)(tmp + NE);                              // NE
    float* stats = (float*)(eidx + NE);                          // 512
    int* deg    = (int*)(stats + 512);                           // NN (adjacent to stats)
    int* off    = deg + NN;                                      // NN+1
    int* bsum   = off + (NN + 1);                                // 64
    int* gcursor = bsum + 64;                                    // NB
    float* z    = out;                                           // pre-norm z in d_out

    // ---- CSR build (bucketed two-phase) ----
    const int zn = 512 + NN;
    zero_kernel<<<(zn + 255) / 256, 256, 0, stream>>>((int*)stats, zn);
    deg_kernel<<<(NE + 255) / 256, 256, 0, stream>>>(dst, deg);
    const int nblk = (NN + 1023) / 1024;
    scan1_kernel<<<nblk, 1024, 0, stream>>>(deg, off, bsum);
    scan2_kernel<<<1, 64, 0, stream>>>(bsum, nblk);
    scan3_kernel<<<(NN + 255) / 256, 256, 0, stream>>>(off, bsum, gcursor);
    binA_kernel<<<(NE + CHUNK - 1) / CHUNK, 256, 0, stream>>>(src, dst, gcursor, tmp);
    binB_kernel<<<NB, 256, 0, stream>>>(tmp, off, eidx);

    const int gemmblk   = (NN + 127) / 128;
    const int gatherblk = (NN * 8 + 255) / 256;
    const int thrblk    = (NN * 16 + 255) / 256;

    float* gs0 = stats + 0 * 128;
    proj_kernel<128, false><<<gemmblk, 256, 0, stream>>>(
        h, W1_0, nullptr, nullptr, nullptr, nullptr, p);
    gather_kernel<<<gatherblk, 256, 0, stream>>>(p, off, eidx, b1_0, Y);
    mlp2_kernel<<<gemmblk, 256, 0, stream>>>(Y, W2_0, b2_0, z, gs0, gs0 + 64);

    const float* gammas[4] = { g_0, gst + 0, gst + 64, gst + 128 };
    const float* betas[4]  = { be_0, best + 0, best + 64, best + 128 };

    for (int l = 0; l < 3; ++l) {
        float* gsp = stats + l * 128;
        float* gsc = stats + (l + 1) * 128;
        proj_kernel<64, true><<<gemmblk, 256, 0, stream>>>(
            z, W1st + l * 4096, gsp, gsp + 64, gammas[l], betas[l], p);
        gather_kernel<<<gatherblk, 256, 0, stream>>>(p, off, eidx, b1st + l * 64, Y);
        mlp2_kernel<<<gemmblk, 256, 0, stream>>>(
            Y, W2st + l * 4096, b2st + l * 64, z, gsc, gsc + 64);
    }

    float* gs3 = stats + 3 * 128;
    norm_kernel<<<thrblk, 256, 0, stream>>>(z, gs3, gs3 + 64, gammas[3], betas[3], out);
}

// Round 9
// 257.984 us; speedup vs baseline: 1.7974x; 1.1668x over previous
//
#include <hip/hip_runtime.h>
#include <hip/hip_bf16.h>

static constexpr int NN = 50000;
static constexpr int NE = 800000;
static constexpr float BN_EPS = 1e-5f;

static constexpr int NB  = 128;    // dst buckets
static constexpr int NPB = 391;    // nodes per bucket (128*391 = 50048 >= NN)
static constexpr int CAP = 8192;   // tmp slots per bucket (max bucket ~6600)
static constexpr int CHUNK = 2048;

__device__ __forceinline__ float bflo(unsigned u) { return __uint_as_float(u << 16); }
__device__ __forceinline__ float bfhi(unsigned u) { return __uint_as_float(u & 0xffff0000u); }
__device__ __forceinline__ unsigned short f2bf(float f) {
    unsigned u = __float_as_uint(f);
    unsigned r = (u + 0x7fffu + ((u >> 16) & 1u)) >> 16;
    return (unsigned short)r;
}

// ===========================================================================
// zero: stats (512 f) + gcount (NB ints), contiguous
// ===========================================================================
__global__ __launch_bounds__(256) void zero_kernel(int* __restrict__ ptr, int n)
{
    int i = blockIdx.x * 256 + threadIdx.x;
    if (i < n) ptr[i] = 0;
}

// ===========================================================================
// binA: LDS-bin edges by dst bucket, flush runs to fixed-cap bucket-major tmp.
// gcount[b] accumulates per-bucket edge counts (starts at 0).
// ===========================================================================
__global__ __launch_bounds__(256) void binA_kernel(
    const int* __restrict__ src, const int* __restrict__ dst,
    int* __restrict__ gcount, unsigned long long* __restrict__ tmp)
{
    __shared__ unsigned long long stage[CHUNK];
    __shared__ int hist[NB], base[NB], gpos[NB];

    const int t = threadIdx.x;
    const int cb = blockIdx.x * CHUNK;
    const int total = min(CHUNK, NE - cb);

    if (t < NB) hist[t] = 0;
    __syncthreads();

    int mb[8], mslot[8];
    unsigned long long mv[8];
    #pragma unroll
    for (int k = 0; k < 8; ++k) {
        int e = cb + k * 256 + t;
        mb[k] = -1;
        if (e < NE) {
            int s = src[e];
            int d = dst[e];
            int b = d / NPB;
            mb[k] = b;
            mv[k] = ((unsigned long long)(unsigned)d << 32) | (unsigned)s;
            mslot[k] = atomicAdd(&hist[b], 1);
        }
    }
    __syncthreads();

    if (t < NB) base[t] = hist[t];
    __syncthreads();
    for (int ofs = 1; ofs < NB; ofs <<= 1) {
        int v = (t >= ofs && t < NB) ? base[t - ofs] : 0;
        __syncthreads();
        if (t < NB) base[t] += v;
        __syncthreads();
    }
    if (t < NB && hist[t] > 0)
        gpos[t] = t * CAP + atomicAdd(&gcount[t], hist[t]);
    __syncthreads();

    #pragma unroll
    for (int k = 0; k < 8; ++k) {
        if (mb[k] >= 0) {
            int b = mb[k];
            stage[(base[b] - hist[b]) + mslot[k]] = mv[k];
        }
    }
    __syncthreads();

    for (int i = t; i < total; i += 256) {
        unsigned long long v = stage[i];
        int b = (int)(v >> 32) / NPB;
        int pos = gpos[b] + (i - (base[b] - hist[b]));
        tmp[pos] = v;
    }
}

// ===========================================================================
// binB: one block per bucket. Histogram its edges over its nodes, LDS scan
// -> writes global off AND scatters src into eidx. Replaces deg+scan1/2/3.
// ===========================================================================
__global__ __launch_bounds__(256) void binB_kernel(
    const unsigned long long* __restrict__ tmp, const int* __restrict__ gcount,
    int* __restrict__ off, int* __restrict__ eidx)
{
    __shared__ int gb[NB];
    __shared__ int hist[NPB];
    __shared__ int hs[512];
    __shared__ int cur[NPB];
    __shared__ int base_s;

    const int t = threadIdx.x;
    const int b = blockIdx.x;
    const int n0 = b * NPB;
    const int n1 = min(n0 + NPB, NN);
    const int nnodes = n1 - n0;
    const int cnt = gcount[b];

    if (t < NB) gb[t] = gcount[t];
    for (int n = t; n < NPB; n += 256) hist[n] = 0;
    __syncthreads();
    // inclusive scan over bucket counts -> this bucket's global base
    for (int ofs = 1; ofs < NB; ofs <<= 1) {
        int v = (t >= ofs && t < NB) ? gb[t - ofs] : 0;
        __syncthreads();
        if (t < NB) gb[t] += v;
        __syncthreads();
    }
    if (t == 0) base_s = (b == 0) ? 0 : gb[b - 1];
    __syncthreads();
    const int base = base_s;

    const unsigned long long* tb = tmp + (size_t)b * CAP;
    for (int i = t; i < cnt; i += 256) {
        int d = (int)(tb[i] >> 32);
        atomicAdd(&hist[d - n0], 1);
    }
    __syncthreads();
    // inclusive Hillis-Steele scan of hist, padded to 512 (2 elems/thread)
    hs[t] = (t < NPB) ? hist[t] : 0;
    hs[t + 256] = (t + 256 < NPB) ? hist[t + 256] : 0;
    __syncthreads();
    for (int ofs = 1; ofs < 512; ofs <<= 1) {
        int a0 = (t >= ofs) ? hs[t - ofs] : 0;
        int a1 = hs[t + 256 - ofs];
        __syncthreads();
        hs[t] += a0;
        hs[t + 256] += a1;
        __syncthreads();
    }
    // off + local cursors (exclusive = inclusive - self)
    for (int n = t; n < nnodes; n += 256) {
        int excl = hs[n] - hist[n];
        off[n0 + n] = base + excl;
        cur[n] = base + excl;
    }
    if (b == NB - 1 && t == 0) off[NN] = base + cnt;
    __syncthreads();
    // scatter into this bucket's private eidx window
    for (int i = t; i < cnt; i += 256) {
        unsigned long long v = tb[i];
        int d = (int)(v >> 32);
        int pos = atomicAdd(&cur[d - n0], 1);
        eidx[pos] = (int)(v & 0xffffffffu);
    }
}

// ===========================================================================
// proj: p(bf16) = act(hin) @ W1.  act = identity or BN(scale/shift)+relu.
// 128 rows/block, tile 4x8.
// ===========================================================================
template<int D, bool NORM>
__global__ __launch_bounds__(256) void proj_kernel(
    const float* __restrict__ hin, const float* __restrict__ W1,
    const float* __restrict__ gsum, const float* __restrict__ gsq,
    const float* __restrict__ gamma, const float* __restrict__ beta,
    unsigned short* __restrict__ p)
{
    constexpr int RPB = 128;
    __shared__ float XsT[64][132];
    __shared__ float Ws[64][64];
    __shared__ float scs[64], shs[64];

    const int t = threadIdx.x;
    const int rowbase = blockIdx.x * RPB;

    if (NORM) {
        if (t < 64) {
            const float invn = 1.f / (float)NN;
            float mean = gsum[t] * invn;
            float var  = gsq[t] * invn - mean * mean;
            float sc   = gamma[t] * rsqrtf(var + BN_EPS);
            scs[t] = sc;
            shs[t] = beta[t] - mean * sc;
        }
        __syncthreads();
    }

    const int tc = t & 7;
    const int tr = t >> 3;
    const int c0 = tc * 8;
    const int r0 = tr * 4;

    float acc[4][8];
    #pragma unroll
    for (int i = 0; i < 4; ++i)
        #pragma unroll
        for (int j = 0; j < 8; ++j) acc[i][j] = 0.f;

    for (int kc = 0; kc < D; kc += 64) {
        if (kc) __syncthreads();
        {
            const float4* wg = reinterpret_cast<const float4*>(W1 + (size_t)kc * 64);
            float4* wl = reinterpret_cast<float4*>(&Ws[0][0]);
            for (int i = t; i < 64 * 16; i += 256) wl[i] = wg[i];
        }
        {
            int rr = t & 15, q = t >> 4;
            for (int i = 0; i < RPB; i += 16) {
                int r = i + rr;
                int gr = rowbase + r;
                float4 v = make_float4(0.f, 0.f, 0.f, 0.f);
                if (gr < NN) {
                    v = reinterpret_cast<const float4*>(hin + (size_t)gr * D + kc)[q];
                    if (NORM) {
                        int c = q * 4;
                        v.x = fmaxf(v.x * scs[c + 0] + shs[c + 0], 0.f);
                        v.y = fmaxf(v.y * scs[c + 1] + shs[c + 1], 0.f);
                        v.z = fmaxf(v.z * scs[c + 2] + shs[c + 2], 0.f);
                        v.w = fmaxf(v.w * scs[c + 3] + shs[c + 3], 0.f);
                    }
                }
                XsT[q * 4 + 0][r] = v.x;
                XsT[q * 4 + 1][r] = v.y;
                XsT[q * 4 + 2][r] = v.z;
                XsT[q * 4 + 3][r] = v.w;
            }
        }
        __syncthreads();

        for (int k = 0; k < 64; ++k) {
            float4 xa = *reinterpret_cast<const float4*>(&XsT[k][r0]);
            float4 wa = *reinterpret_cast<const float4*>(&Ws[k][c0]);
            float4 wb = *reinterpret_cast<const float4*>(&Ws[k][c0 + 4]);
            float x[4] = { xa.x, xa.y, xa.z, xa.w };
            float w[8] = { wa.x, wa.y, wa.z, wa.w, wb.x, wb.y, wb.z, wb.w };
            #pragma unroll
            for (int i = 0; i < 4; ++i)
                #pragma unroll
                for (int j = 0; j < 8; ++j) acc[i][j] += x[i] * w[j];
        }
    }

    #pragma unroll
    for (int i = 0; i < 4; ++i) {
        int gr = rowbase + r0 + i;
        if (gr < NN) {
            uint4 u;
            u.x = (unsigned)f2bf(acc[i][0]) | ((unsigned)f2bf(acc[i][1]) << 16);
            u.y = (unsigned)f2bf(acc[i][2]) | ((unsigned)f2bf(acc[i][3]) << 16);
            u.z = (unsigned)f2bf(acc[i][4]) | ((unsigned)f2bf(acc[i][5]) << 16);
            u.w = (unsigned)f2bf(acc[i][6]) | ((unsigned)f2bf(acc[i][7]) << 16);
            *reinterpret_cast<uint4*>(p + (size_t)gr * 64 + c0) = u;
        }
    }
}

// ===========================================================================
// gather: Y[i] = relu(p[i] + sum_{j in N(i)} p[j] + b1)   (bf16 in/out)
// ===========================================================================
__global__ __launch_bounds__(256) void gather_kernel(
    const unsigned short* __restrict__ p, const int* __restrict__ off,
    const int* __restrict__ eidx, const float* __restrict__ b1,
    unsigned short* __restrict__ Y)
{
    int gid = blockIdx.x * 256 + threadIdx.x;
    if (gid >= NN * 8) return;
    int row = gid >> 3;
    int q = gid & 7;

    const uint4* pb = reinterpret_cast<const uint4*>(p);
    uint4 u = pb[row * 8 + q];
    float a0 = bflo(u.x), a1 = bfhi(u.x), a2 = bflo(u.y), a3 = bfhi(u.y);
    float a4 = bflo(u.z), a5 = bfhi(u.z), a6 = bflo(u.w), a7 = bfhi(u.w);

    int e = off[row];
    const int end = off[row + 1];
    for (; e + 4 <= end; e += 4) {
        int s0 = eidx[e + 0], s1 = eidx[e + 1];
        int s2 = eidx[e + 2], s3 = eidx[e + 3];
        uint4 v0 = pb[s0 * 8 + q];
        uint4 v1 = pb[s1 * 8 + q];
        uint4 v2 = pb[s2 * 8 + q];
        uint4 v3 = pb[s3 * 8 + q];
        a0 += (bflo(v0.x) + bflo(v1.x)) + (bflo(v2.x) + bflo(v3.x));
        a1 += (bfhi(v0.x) + bfhi(v1.x)) + (bfhi(v2.x) + bfhi(v3.x));
        a2 += (bflo(v0.y) + bflo(v1.y)) + (bflo(v2.y) + bflo(v3.y));
        a3 += (bfhi(v0.y) + bfhi(v1.y)) + (bfhi(v2.y) + bfhi(v3.y));
        a4 += (bflo(v0.z) + bflo(v1.z)) + (bflo(v2.z) + bflo(v3.z));
        a5 += (bfhi(v0.z) + bfhi(v1.z)) + (bfhi(v2.z) + bfhi(v3.z));
        a6 += (bflo(v0.w) + bflo(v1.w)) + (bflo(v2.w) + bflo(v3.w));
        a7 += (bfhi(v0.w) + bfhi(v1.w)) + (bfhi(v2.w) + bfhi(v3.w));
    }
    for (; e < end; ++e) {
        uint4 v = pb[eidx[e] * 8 + q];
        a0 += bflo(v.x); a1 += bfhi(v.x); a2 += bflo(v.y); a3 += bfhi(v.y);
        a4 += bflo(v.z); a5 += bfhi(v.z); a6 += bflo(v.w); a7 += bfhi(v.w);
    }

    float4 blo = reinterpret_cast<const float4*>(b1)[q * 2];
    float4 bhi = reinterpret_cast<const float4*>(b1)[q * 2 + 1];
    a0 = fmaxf(a0 + blo.x, 0.f); a1 = fmaxf(a1 + blo.y, 0.f);
    a2 = fmaxf(a2 + blo.z, 0.f); a3 = fmaxf(a3 + blo.w, 0.f);
    a4 = fmaxf(a4 + bhi.x, 0.f); a5 = fmaxf(a5 + bhi.y, 0.f);
    a6 = fmaxf(a6 + bhi.z, 0.f); a7 = fmaxf(a7 + bhi.w, 0.f);

    uint4 o;
    o.x = (unsigned)f2bf(a0) | ((unsigned)f2bf(a1) << 16);
    o.y = (unsigned)f2bf(a2) | ((unsigned)f2bf(a3) << 16);
    o.z = (unsigned)f2bf(a4) | ((unsigned)f2bf(a5) << 16);
    o.w = (unsigned)f2bf(a6) | ((unsigned)f2bf(a7) << 16);
    reinterpret_cast<uint4*>(Y)[row * 8 + q] = o;
}

// ===========================================================================
// mlp2: z = Y @ W2 + b2 (Y bf16 -> fp32 math), store z fp32, BN stats.
// ===========================================================================
__global__ __launch_bounds__(256) void mlp2_kernel(
    const unsigned short* __restrict__ Y, const float* __restrict__ W2,
    const float* __restrict__ b2, float* __restrict__ z,
    float* __restrict__ gsum, float* __restrict__ gsq)
{
    constexpr int RPB = 128;
    __shared__ float XsT[64][132];
    __shared__ float Ws[64][64];
    __shared__ float b2s[64], lsum[64], lsq[64];

    const int t = threadIdx.x;
    const int rowbase = blockIdx.x * RPB;

    if (t < 64) { b2s[t] = b2[t]; lsum[t] = 0.f; lsq[t] = 0.f; }

    {
        const float4* wg = reinterpret_cast<const float4*>(W2);
        float4* wl = reinterpret_cast<float4*>(&Ws[0][0]);
        for (int i = t; i < 64 * 16; i += 256) wl[i] = wg[i];
    }
    {
        const uint4* yb = reinterpret_cast<const uint4*>(Y);
        int rr = t & 31, qq = t >> 5;
        for (int i = 0; i < RPB; i += 32) {
            int r = i + rr;
            int gr = rowbase + r;
            uint4 v = make_uint4(0u, 0u, 0u, 0u);
            if (gr < NN) v = yb[gr * 8 + qq];
            int c = qq * 8;
            XsT[c + 0][r] = bflo(v.x); XsT[c + 1][r] = bfhi(v.x);
            XsT[c + 2][r] = bflo(v.y); XsT[c + 3][r] = bfhi(v.y);
            XsT[c + 4][r] = bflo(v.z); XsT[c + 5][r] = bfhi(v.z);
            XsT[c + 6][r] = bflo(v.w); XsT[c + 7][r] = bfhi(v.w);
        }
    }
    __syncthreads();

    const int tc = t & 7;
    const int tr = t >> 3;
    const int c0 = tc * 8;
    const int r0 = tr * 4;

    float acc[4][8];
    #pragma unroll
    for (int i = 0; i < 4; ++i)
        #pragma unroll
        for (int j = 0; j < 8; ++j) acc[i][j] = 0.f;

    for (int k = 0; k < 64; ++k) {
        float4 xa = *reinterpret_cast<const float4*>(&XsT[k][r0]);
        float4 wa = *reinterpret_cast<const float4*>(&Ws[k][c0]);
        float4 wb = *reinterpret_cast<const float4*>(&Ws[k][c0 + 4]);
        float x[4] = { xa.x, xa.y, xa.z, xa.w };
        float w[8] = { wa.x, wa.y, wa.z, wa.w, wb.x, wb.y, wb.z, wb.w };
        #pragma unroll
        for (int i = 0; i < 4; ++i)
            #pragma unroll
            for (int j = 0; j < 8; ++j) acc[i][j] += x[i] * w[j];
    }

    float s[8], sq[8];
    #pragma unroll
    for (int j = 0; j < 8; ++j) { s[j] = 0.f; sq[j] = 0.f; }

    #pragma unroll
    for (int i = 0; i < 4; ++i) {
        int gr = rowbase + r0 + i;
        if (gr < NN) {
            float zv[8];
            #pragma unroll
            for (int j = 0; j < 8; ++j) {
                zv[j] = acc[i][j] + b2s[c0 + j];
                s[j] += zv[j];
                sq[j] += zv[j] * zv[j];
            }
            float4 lo = make_float4(zv[0], zv[1], zv[2], zv[3]);
            float4 hi = make_float4(zv[4], zv[5], zv[6], zv[7]);
            *reinterpret_cast<float4*>(z + (size_t)gr * 64 + c0) = lo;
            *reinterpret_cast<float4*>(z + (size_t)gr * 64 + c0 + 4) = hi;
        }
    }

    #pragma unroll
    for (int j = 0; j < 8; ++j) {
        s[j]  += __shfl_xor(s[j], 8);
        s[j]  += __shfl_xor(s[j], 16);
        s[j]  += __shfl_xor(s[j], 32);
        sq[j] += __shfl_xor(sq[j], 8);
        sq[j] += __shfl_xor(sq[j], 16);
        sq[j] += __shfl_xor(sq[j], 32);
    }
    if ((t & 56) == 0) {
        #pragma unroll
        for (int j = 0; j < 8; ++j) {
            atomicAdd(&lsum[c0 + j], s[j]);
            atomicAdd(&lsq[c0 + j], sq[j]);
        }
    }
    __syncthreads();
    if (t < 64) {
        atomicAdd(&gsum[t], lsum[t]);
        atomicAdd(&gsq[t], lsq[t]);
    }
}

// ===========================================================================
// final norm: out = relu(z*scale+shift)
// ===========================================================================
__global__ __launch_bounds__(256) void norm_kernel(
    const float* __restrict__ z,
    const float* __restrict__ gsum, const float* __restrict__ gsq,
    const float* __restrict__ gamma, const float* __restrict__ beta,
    float* __restrict__ out)
{
    __shared__ float sc[64], sh[64];
    int t = threadIdx.x;
    if (t < 64) {
        const float invn = 1.f / (float)NN;
        float mean = gsum[t] * invn;
        float var  = gsq[t] * invn - mean * mean;
        float s    = gamma[t] * rsqrtf(var + BN_EPS);
        sc[t] = s;
        sh[t] = beta[t] - mean * s;
    }
    __syncthreads();
    int idx = blockIdx.x * 256 + t;
    if (idx >= NN * 16) return;
    int c = (idx & 15) * 4;
    float4 v = reinterpret_cast<const float4*>(z)[idx];
    v.x = fmaxf(v.x * sc[c + 0] + sh[c + 0], 0.f);
    v.y = fmaxf(v.y * sc[c + 1] + sh[c + 1], 0.f);
    v.z = fmaxf(v.z * sc[c + 2] + sh[c + 2], 0.f);
    v.w = fmaxf(v.w * sc[c + 3] + sh[c + 3], 0.f);
    reinterpret_cast<float4*>(out)[idx] = v;
}

// ===========================================================================
extern "C" void kernel_launch(void* const* d_in, const int* in_sizes, int n_in,
                              void* d_out, int out_size, void* d_ws, size_t ws_size,
                              hipStream_t stream)
{
    const float* h    = (const float*)d_in[0];
    const int*   src  = (const int*)d_in[1];
    const int*   dst  = (const int*)d_in[2];
    const float* W1_0 = (const float*)d_in[3];
    const float* b1_0 = (const float*)d_in[4];
    const float* W2_0 = (const float*)d_in[5];
    const float* b2_0 = (const float*)d_in[6];
    const float* g_0  = (const float*)d_in[7];
    const float* be_0 = (const float*)d_in[8];
    const float* W1st = (const float*)d_in[9];
    const float* b1st = (const float*)d_in[10];
    const float* W2st = (const float*)d_in[11];
    const float* b2st = (const float*)d_in[12];
    const float* gst  = (const float*)d_in[13];
    const float* best = (const float*)d_in[14];
    float* out = (float*)d_out;

    char* ws = (char*)d_ws;
    unsigned short* p = (unsigned short*)ws;                     // NN*64 bf16
    unsigned short* Y = p + (size_t)NN * 64;                     // NN*64 bf16
    unsigned long long* tmp = (unsigned long long*)(Y + (size_t)NN * 64);  // NB*CAP u64
    int* eidx   = (int*)(tmp + (size_t)NB * CAP);                // NE
    float* stats = (float*)(eidx + NE);                          // 512 floats
    int* gcount = (int*)(stats + 512);                           // NB (adjacent: one zero)
    int* off    = gcount + NB;                                   // NN+1
    float* z    = out;                                           // pre-norm z in d_out

    // ---- CSR build: zero -> binA (bucket) -> binB (hist+scan+off+scatter) --
    zero_kernel<<<3, 256, 0, stream>>>((int*)stats, 512 + NB);
    binA_kernel<<<(NE + CHUNK - 1) / CHUNK, 256, 0, stream>>>(src, dst, gcount, tmp);
    binB_kernel<<<NB, 256, 0, stream>>>(tmp, gcount, off, eidx);

    const int gemmblk   = (NN + 127) / 128;
    const int gatherblk = (NN * 8 + 255) / 256;
    const int thrblk    = (NN * 16 + 255) / 256;

    float* gs0 = stats + 0 * 128;
    proj_kernel<128, false><<<gemmblk, 256, 0, stream>>>(
        h, W1_0, nullptr, nullptr, nullptr, nullptr, p);
    gather_kernel<<<gatherblk, 256, 0, stream>>>(p, off, eidx, b1_0, Y);
    mlp2_kernel<<<gemmblk, 256, 0, stream>>>(Y, W2_0, b2_0, z, gs0, gs0 + 64);

    const float* gammas[4] = { g_0, gst + 0, gst + 64, gst + 128 };
    const float* betas[4]  = { be_0, best + 0, best + 64, best + 128 };

    for (int l = 0; l < 3; ++l) {
        float* gsp = stats + l * 128;
        float* gsc = stats + (l + 1) * 128;
        proj_kernel<64, true><<<gemmblk, 256, 0, stream>>>(
            z, W1st + l * 4096, gsp, gsp + 64, gammas[l], betas[l], p);
        gather_kernel<<<gatherblk, 256, 0, stream>>>(p, off, eidx, b1st + l * 64, Y);
        mlp2_kernel<<<gemmblk, 256, 0, stream>>>(
            Y, W2st + l * 4096, b2st + l * 64, z, gsc, gsc + 64);
    }

    float* gs3 = stats + 3 * 128;
    norm_kernel<<<thrblk, 256, 0, stream>>>(z, gs3, gs3 + 64, gammas[3], betas[3], out);
}

// Round 10
// 256.247 us; speedup vs baseline: 1.8095x; 1.0068x over previous
//
#include <hip/hip_runtime.h>
#include <hip/hip_bf16.h>

static constexpr int NN = 50000;
static constexpr int NE = 800000;
static constexpr float BN_EPS = 1e-5f;

static constexpr int NB  = 128;    // dst buckets
static constexpr int NPB = 391;    // nodes per bucket (128*391 = 50048 >= NN)
static constexpr int CAP = 8192;   // tmp slots per bucket (max bucket ~6600)
static constexpr int CHUNK = 2048;

__device__ __forceinline__ float bflo(unsigned u) { return __uint_as_float(u << 16); }
__device__ __forceinline__ float bfhi(unsigned u) { return __uint_as_float(u & 0xffff0000u); }
__device__ __forceinline__ unsigned short f2bf(float f) {
    unsigned u = __float_as_uint(f);
    unsigned r = (u + 0x7fffu + ((u >> 16) & 1u)) >> 16;
    return (unsigned short)r;
}

// ===========================================================================
// zero: stats (512 f) + gcount (NB ints), contiguous
// ===========================================================================
__global__ __launch_bounds__(256) void zero_kernel(int* __restrict__ ptr, int n)
{
    int i = blockIdx.x * 256 + threadIdx.x;
    if (i < n) ptr[i] = 0;
}

// ===========================================================================
// binA: LDS-bin edges by dst bucket into fixed-cap bucket-major tmp (u32:
// (dst<<16)|src, both < 65536). gcount[b] accumulates bucket counts.
// ===========================================================================
__global__ __launch_bounds__(256) void binA_kernel(
    const int* __restrict__ src, const int* __restrict__ dst,
    int* __restrict__ gcount, unsigned* __restrict__ tmp)
{
    __shared__ unsigned stage[CHUNK];
    __shared__ int hist[NB], base[NB], gpos[NB];

    const int t = threadIdx.x;
    const int cb = blockIdx.x * CHUNK;
    const int total = min(CHUNK, NE - cb);

    if (t < NB) hist[t] = 0;
    __syncthreads();

    int mb[8], mslot[8];
    unsigned mv[8];
    #pragma unroll
    for (int k = 0; k < 8; ++k) {
        int e = cb + k * 256 + t;
        mb[k] = -1;
        if (e < NE) {
            int s = src[e];
            int d = dst[e];
            int b = d / NPB;
            mb[k] = b;
            mv[k] = ((unsigned)d << 16) | (unsigned)s;
            mslot[k] = atomicAdd(&hist[b], 1);
        }
    }
    __syncthreads();

    if (t < NB) base[t] = hist[t];
    __syncthreads();
    for (int ofs = 1; ofs < NB; ofs <<= 1) {
        int v = (t >= ofs && t < NB) ? base[t - ofs] : 0;
        __syncthreads();
        if (t < NB) base[t] += v;
        __syncthreads();
    }
    if (t < NB && hist[t] > 0)
        gpos[t] = t * CAP + atomicAdd(&gcount[t], hist[t]);
    __syncthreads();

    #pragma unroll
    for (int k = 0; k < 8; ++k) {
        if (mb[k] >= 0) {
            int b = mb[k];
            stage[(base[b] - hist[b]) + mslot[k]] = mv[k];
        }
    }
    __syncthreads();

    for (int i = t; i < total; i += 256) {
        unsigned v = stage[i];
        int b = (int)(v >> 16) / NPB;
        int pos = gpos[b] + (i - (base[b] - hist[b]));
        tmp[pos] = v;
    }
}

// ===========================================================================
// binB: one block per bucket. Histogram edges over its nodes, LDS scan ->
// writes global off AND scatters src into eidx.
// ===========================================================================
__global__ __launch_bounds__(256) void binB_kernel(
    const unsigned* __restrict__ tmp, const int* __restrict__ gcount,
    int* __restrict__ off, int* __restrict__ eidx)
{
    __shared__ int gb[NB];
    __shared__ int hist[NPB];
    __shared__ int hs[512];
    __shared__ int cur[NPB];
    __shared__ int base_s;

    const int t = threadIdx.x;
    const int b = blockIdx.x;
    const int n0 = b * NPB;
    const int n1 = min(n0 + NPB, NN);
    const int nnodes = n1 - n0;
    const int cnt = gcount[b];

    if (t < NB) gb[t] = gcount[t];
    for (int n = t; n < NPB; n += 256) hist[n] = 0;
    __syncthreads();
    for (int ofs = 1; ofs < NB; ofs <<= 1) {
        int v = (t >= ofs && t < NB) ? gb[t - ofs] : 0;
        __syncthreads();
        if (t < NB) gb[t] += v;
        __syncthreads();
    }
    if (t == 0) base_s = (b == 0) ? 0 : gb[b - 1];
    __syncthreads();
    const int base = base_s;

    const unsigned* tb = tmp + (size_t)b * CAP;
    for (int i = t; i < cnt; i += 256) {
        int d = (int)(tb[i] >> 16);
        atomicAdd(&hist[d - n0], 1);
    }
    __syncthreads();
    hs[t] = (t < NPB) ? hist[t] : 0;
    hs[t + 256] = (t + 256 < NPB) ? hist[t + 256] : 0;
    __syncthreads();
    for (int ofs = 1; ofs < 512; ofs <<= 1) {
        int a0 = (t >= ofs) ? hs[t - ofs] : 0;
        int a1 = hs[t + 256 - ofs];
        __syncthreads();
        hs[t] += a0;
        hs[t + 256] += a1;
        __syncthreads();
    }
    for (int n = t; n < nnodes; n += 256) {
        int excl = hs[n] - hist[n];
        off[n0 + n] = base + excl;
        cur[n] = base + excl;
    }
    if (b == NB - 1 && t == 0) off[NN] = base + cnt;
    __syncthreads();
    for (int i = t; i < cnt; i += 256) {
        unsigned v = tb[i];
        int d = (int)(v >> 16);
        int pos = atomicAdd(&cur[d - n0], 1);
        eidx[pos] = (int)(v & 0xffffu);
    }
}

// ===========================================================================
// proj: p(bf16) = act(hin) @ W1.
//   NORM=false: hin fp32 [NN][D] (layer 0 input)
//   NORM=true : hin bf16 [NN][64] (zb), apply BN(scale/shift)+relu on load
// 128 rows/block, tile 4x8.
// ===========================================================================
template<int D, bool NORM>
__global__ __launch_bounds__(256) void proj_kernel(
    const void* __restrict__ hin_, const float* __restrict__ W1,
    const float* __restrict__ gsum, const float* __restrict__ gsq,
    const float* __restrict__ gamma, const float* __restrict__ beta,
    unsigned short* __restrict__ p)
{
    constexpr int RPB = 128;
    __shared__ float XsT[64][132];
    __shared__ float Ws[64][64];
    __shared__ float scs[64], shs[64];

    const int t = threadIdx.x;
    const int rowbase = blockIdx.x * RPB;

    if (NORM) {
        if (t < 64) {
            const float invn = 1.f / (float)NN;
            float mean = gsum[t] * invn;
            float var  = gsq[t] * invn - mean * mean;
            float sc   = gamma[t] * rsqrtf(var + BN_EPS);
            scs[t] = sc;
            shs[t] = beta[t] - mean * sc;
        }
        __syncthreads();
    }

    const int tc = t & 7;
    const int tr = t >> 3;
    const int c0 = tc * 8;
    const int r0 = tr * 4;

    float acc[4][8];
    #pragma unroll
    for (int i = 0; i < 4; ++i)
        #pragma unroll
        for (int j = 0; j < 8; ++j) acc[i][j] = 0.f;

    for (int kc = 0; kc < D; kc += 64) {
        if (kc) __syncthreads();
        {
            const float4* wg = reinterpret_cast<const float4*>(W1 + (size_t)kc * 64);
            float4* wl = reinterpret_cast<float4*>(&Ws[0][0]);
            for (int i = t; i < 64 * 16; i += 256) wl[i] = wg[i];
        }
        if constexpr (NORM) {
            // bf16 input, D == 64: 8 channels (uint4) per thread
            const uint4* hb = reinterpret_cast<const uint4*>(hin_);
            int rr = t & 31, q = t >> 5;       // q 0..7
            for (int i = 0; i < RPB; i += 32) {
                int r = i + rr;
                int gr = rowbase + r;
                uint4 v = make_uint4(0u, 0u, 0u, 0u);
                if (gr < NN) v = hb[gr * 8 + q];
                int c = q * 8;
                float f0 = bflo(v.x), f1 = bfhi(v.x), f2 = bflo(v.y), f3 = bfhi(v.y);
                float f4 = bflo(v.z), f5 = bfhi(v.z), f6 = bflo(v.w), f7 = bfhi(v.w);
                XsT[c + 0][r] = fmaxf(f0 * scs[c + 0] + shs[c + 0], 0.f);
                XsT[c + 1][r] = fmaxf(f1 * scs[c + 1] + shs[c + 1], 0.f);
                XsT[c + 2][r] = fmaxf(f2 * scs[c + 2] + shs[c + 2], 0.f);
                XsT[c + 3][r] = fmaxf(f3 * scs[c + 3] + shs[c + 3], 0.f);
                XsT[c + 4][r] = fmaxf(f4 * scs[c + 4] + shs[c + 4], 0.f);
                XsT[c + 5][r] = fmaxf(f5 * scs[c + 5] + shs[c + 5], 0.f);
                XsT[c + 6][r] = fmaxf(f6 * scs[c + 6] + shs[c + 6], 0.f);
                XsT[c + 7][r] = fmaxf(f7 * scs[c + 7] + shs[c + 7], 0.f);
            }
        } else {
            const float* hin = reinterpret_cast<const float*>(hin_);
            int rr = t & 15, q = t >> 4;
            for (int i = 0; i < RPB; i += 16) {
                int r = i + rr;
                int gr = rowbase + r;
                float4 v = make_float4(0.f, 0.f, 0.f, 0.f);
                if (gr < NN)
                    v = reinterpret_cast<const float4*>(hin + (size_t)gr * D + kc)[q];
                XsT[q * 4 + 0][r] = v.x;
                XsT[q * 4 + 1][r] = v.y;
                XsT[q * 4 + 2][r] = v.z;
                XsT[q * 4 + 3][r] = v.w;
            }
        }
        __syncthreads();

        for (int k = 0; k < 64; ++k) {
            float4 xa = *reinterpret_cast<const float4*>(&XsT[k][r0]);
            float4 wa = *reinterpret_cast<const float4*>(&Ws[k][c0]);
            float4 wb = *reinterpret_cast<const float4*>(&Ws[k][c0 + 4]);
            float x[4] = { xa.x, xa.y, xa.z, xa.w };
            float w[8] = { wa.x, wa.y, wa.z, wa.w, wb.x, wb.y, wb.z, wb.w };
            #pragma unroll
            for (int i = 0; i < 4; ++i)
                #pragma unroll
                for (int j = 0; j < 8; ++j) acc[i][j] += x[i] * w[j];
        }
    }

    #pragma unroll
    for (int i = 0; i < 4; ++i) {
        int gr = rowbase + r0 + i;
        if (gr < NN) {
            uint4 u;
            u.x = (unsigned)f2bf(acc[i][0]) | ((unsigned)f2bf(acc[i][1]) << 16);
            u.y = (unsigned)f2bf(acc[i][2]) | ((unsigned)f2bf(acc[i][3]) << 16);
            u.z = (unsigned)f2bf(acc[i][4]) | ((unsigned)f2bf(acc[i][5]) << 16);
            u.w = (unsigned)f2bf(acc[i][6]) | ((unsigned)f2bf(acc[i][7]) << 16);
            *reinterpret_cast<uint4*>(p + (size_t)gr * 64 + c0) = u;
        }
    }
}

// ===========================================================================
// gather: Y[i] = relu(p[i] + sum_{j in N(i)} p[j] + b1)   (bf16 in/out)
// ===========================================================================
__global__ __launch_bounds__(256) void gather_kernel(
    const unsigned short* __restrict__ p, const int* __restrict__ off,
    const int* __restrict__ eidx, const float* __restrict__ b1,
    unsigned short* __restrict__ Y)
{
    int gid = blockIdx.x * 256 + threadIdx.x;
    if (gid >= NN * 8) return;
    int row = gid >> 3;
    int q = gid & 7;

    const uint4* pb = reinterpret_cast<const uint4*>(p);
    uint4 u = pb[row * 8 + q];
    float a0 = bflo(u.x), a1 = bfhi(u.x), a2 = bflo(u.y), a3 = bfhi(u.y);
    float a4 = bflo(u.z), a5 = bfhi(u.z), a6 = bflo(u.w), a7 = bfhi(u.w);

    int e = off[row];
    const int end = off[row + 1];
    for (; e + 4 <= end; e += 4) {
        int s0 = eidx[e + 0], s1 = eidx[e + 1];
        int s2 = eidx[e + 2], s3 = eidx[e + 3];
        uint4 v0 = pb[s0 * 8 + q];
        uint4 v1 = pb[s1 * 8 + q];
        uint4 v2 = pb[s2 * 8 + q];
        uint4 v3 = pb[s3 * 8 + q];
        a0 += (bflo(v0.x) + bflo(v1.x)) + (bflo(v2.x) + bflo(v3.x));
        a1 += (bfhi(v0.x) + bfhi(v1.x)) + (bfhi(v2.x) + bfhi(v3.x));
        a2 += (bflo(v0.y) + bflo(v1.y)) + (bflo(v2.y) + bflo(v3.y));
        a3 += (bfhi(v0.y) + bfhi(v1.y)) + (bfhi(v2.y) + bfhi(v3.y));
        a4 += (bflo(v0.z) + bflo(v1.z)) + (bflo(v2.z) + bflo(v3.z));
        a5 += (bfhi(v0.z) + bfhi(v1.z)) + (bfhi(v2.z) + bfhi(v3.z));
        a6 += (bflo(v0.w) + bflo(v1.w)) + (bflo(v2.w) + bflo(v3.w));
        a7 += (bfhi(v0.w) + bfhi(v1.w)) + (bfhi(v2.w) + bfhi(v3.w));
    }
    for (; e < end; ++e) {
        uint4 v = pb[eidx[e] * 8 + q];
        a0 += bflo(v.x); a1 += bfhi(v.x); a2 += bflo(v.y); a3 += bfhi(v.y);
        a4 += bflo(v.z); a5 += bfhi(v.z); a6 += bflo(v.w); a7 += bfhi(v.w);
    }

    float4 blo = reinterpret_cast<const float4*>(b1)[q * 2];
    float4 bhi = reinterpret_cast<const float4*>(b1)[q * 2 + 1];
    a0 = fmaxf(a0 + blo.x, 0.f); a1 = fmaxf(a1 + blo.y, 0.f);
    a2 = fmaxf(a2 + blo.z, 0.f); a3 = fmaxf(a3 + blo.w, 0.f);
    a4 = fmaxf(a4 + bhi.x, 0.f); a5 = fmaxf(a5 + bhi.y, 0.f);
    a6 = fmaxf(a6 + bhi.z, 0.f); a7 = fmaxf(a7 + bhi.w, 0.f);

    uint4 o;
    o.x = (unsigned)f2bf(a0) | ((unsigned)f2bf(a1) << 16);
    o.y = (unsigned)f2bf(a2) | ((unsigned)f2bf(a3) << 16);
    o.z = (unsigned)f2bf(a4) | ((unsigned)f2bf(a5) << 16);
    o.w = (unsigned)f2bf(a6) | ((unsigned)f2bf(a7) << 16);
    reinterpret_cast<uint4*>(Y)[row * 8 + q] = o;
}

// ===========================================================================
// mlp2: z = Y @ W2 + b2 (Y bf16 -> fp32 math), store z as bf16, BN stats fp32.
// ===========================================================================
__global__ __launch_bounds__(256) void mlp2_kernel(
    const unsigned short* __restrict__ Y, const float* __restrict__ W2,
    const float* __restrict__ b2, unsigned short* __restrict__ zb,
    float* __restrict__ gsum, float* __restrict__ gsq)
{
    constexpr int RPB = 128;
    __shared__ float XsT[64][132];
    __shared__ float Ws[64][64];
    __shared__ float b2s[64], lsum[64], lsq[64];

    const int t = threadIdx.x;
    const int rowbase = blockIdx.x * RPB;

    if (t < 64) { b2s[t] = b2[t]; lsum[t] = 0.f; lsq[t] = 0.f; }

    {
        const float4* wg = reinterpret_cast<const float4*>(W2);
        float4* wl = reinterpret_cast<float4*>(&Ws[0][0]);
        for (int i = t; i < 64 * 16; i += 256) wl[i] = wg[i];
    }
    {
        const uint4* yb = reinterpret_cast<const uint4*>(Y);
        int rr = t & 31, qq = t >> 5;
        for (int i = 0; i < RPB; i += 32) {
            int r = i + rr;
            int gr = rowbase + r;
            uint4 v = make_uint4(0u, 0u, 0u, 0u);
            if (gr < NN) v = yb[gr * 8 + qq];
            int c = qq * 8;
            XsT[c + 0][r] = bflo(v.x); XsT[c + 1][r] = bfhi(v.x);
            XsT[c + 2][r] = bflo(v.y); XsT[c + 3][r] = bfhi(v.y);
            XsT[c + 4][r] = bflo(v.z); XsT[c + 5][r] = bfhi(v.z);
            XsT[c + 6][r] = bflo(v.w); XsT[c + 7][r] = bfhi(v.w);
        }
    }
    __syncthreads();

    const int tc = t & 7;
    const int tr = t >> 3;
    const int c0 = tc * 8;
    const int r0 = tr * 4;

    float acc[4][8];
    #pragma unroll
    for (int i = 0; i < 4; ++i)
        #pragma unroll
        for (int j = 0; j < 8; ++j) acc[i][j] = 0.f;

    for (int k = 0; k < 64; ++k) {
        float4 xa = *reinterpret_cast<const float4*>(&XsT[k][r0]);
        float4 wa = *reinterpret_cast<const float4*>(&Ws[k][c0]);
        float4 wb = *reinterpret_cast<const float4*>(&Ws[k][c0 + 4]);
        float x[4] = { xa.x, xa.y, xa.z, xa.w };
        float w[8] = { wa.x, wa.y, wa.z, wa.w, wb.x, wb.y, wb.z, wb.w };
        #pragma unroll
        for (int i = 0; i < 4; ++i)
            #pragma unroll
            for (int j = 0; j < 8; ++j) acc[i][j] += x[i] * w[j];
    }

    float s[8], sq[8];
    #pragma unroll
    for (int j = 0; j < 8; ++j) { s[j] = 0.f; sq[j] = 0.f; }

    #pragma unroll
    for (int i = 0; i < 4; ++i) {
        int gr = rowbase + r0 + i;
        if (gr < NN) {
            float zv[8];
            #pragma unroll
            for (int j = 0; j < 8; ++j) {
                zv[j] = acc[i][j] + b2s[c0 + j];
                s[j] += zv[j];
                sq[j] += zv[j] * zv[j];
            }
            uint4 o;
            o.x = (unsigned)f2bf(zv[0]) | ((unsigned)f2bf(zv[1]) << 16);
            o.y = (unsigned)f2bf(zv[2]) | ((unsigned)f2bf(zv[3]) << 16);
            o.z = (unsigned)f2bf(zv[4]) | ((unsigned)f2bf(zv[5]) << 16);
            o.w = (unsigned)f2bf(zv[6]) | ((unsigned)f2bf(zv[7]) << 16);
            *reinterpret_cast<uint4*>(zb + (size_t)gr * 64 + c0) = o;
        }
    }

    #pragma unroll
    for (int j = 0; j < 8; ++j) {
        s[j]  += __shfl_xor(s[j], 8);
        s[j]  += __shfl_xor(s[j], 16);
        s[j]  += __shfl_xor(s[j], 32);
        sq[j] += __shfl_xor(sq[j], 8);
        sq[j] += __shfl_xor(sq[j], 16);
        sq[j] += __shfl_xor(sq[j], 32);
    }
    if ((t & 56) == 0) {
        #pragma unroll
        for (int j = 0; j < 8; ++j) {
            atomicAdd(&lsum[c0 + j], s[j]);
            atomicAdd(&lsq[c0 + j], sq[j]);
        }
    }
    __syncthreads();
    if (t < 64) {
        atomicAdd(&gsum[t], lsum[t]);
        atomicAdd(&gsq[t], lsq[t]);
    }
}

// ===========================================================================
// final norm: out(fp32) = relu(zb*scale+shift), zb bf16
// ===========================================================================
__global__ __launch_bounds__(256) void norm_kernel(
    const unsigned short* __restrict__ zb,
    const float* __restrict__ gsum, const float* __restrict__ gsq,
    const float* __restrict__ gamma, const float* __restrict__ beta,
    float* __restrict__ out)
{
    __shared__ float sc[64], sh[64];
    int t = threadIdx.x;
    if (t < 64) {
        const float invn = 1.f / (float)NN;
        float mean = gsum[t] * invn;
        float var  = gsq[t] * invn - mean * mean;
        float s    = gamma[t] * rsqrtf(var + BN_EPS);
        sc[t] = s;
        sh[t] = beta[t] - mean * s;
    }
    __syncthreads();
    int idx = blockIdx.x * 256 + t;
    if (idx >= NN * 8) return;
    int row = idx >> 3;
    int q = idx & 7;
    int c = q * 8;
    uint4 v = reinterpret_cast<const uint4*>(zb)[idx];
    float f0 = bflo(v.x), f1 = bfhi(v.x), f2 = bflo(v.y), f3 = bfhi(v.y);
    float f4 = bflo(v.z), f5 = bfhi(v.z), f6 = bflo(v.w), f7 = bfhi(v.w);
    float4 lo, hi;
    lo.x = fmaxf(f0 * sc[c + 0] + sh[c + 0], 0.f);
    lo.y = fmaxf(f1 * sc[c + 1] + sh[c + 1], 0.f);
    lo.z = fmaxf(f2 * sc[c + 2] + sh[c + 2], 0.f);
    lo.w = fmaxf(f3 * sc[c + 3] + sh[c + 3], 0.f);
    hi.x = fmaxf(f4 * sc[c + 4] + sh[c + 4], 0.f);
    hi.y = fmaxf(f5 * sc[c + 5] + sh[c + 5], 0.f);
    hi.z = fmaxf(f6 * sc[c + 6] + sh[c + 6], 0.f);
    hi.w = fmaxf(f7 * sc[c + 7] + sh[c + 7], 0.f);
    float* o = out + (size_t)row * 64 + c;
    *reinterpret_cast<float4*>(o) = lo;
    *reinterpret_cast<float4*>(o + 4) = hi;
}

// ===========================================================================
extern "C" void kernel_launch(void* const* d_in, const int* in_sizes, int n_in,
                              void* d_out, int out_size, void* d_ws, size_t ws_size,
                              hipStream_t stream)
{
    const float* h    = (const float*)d_in[0];
    const int*   src  = (const int*)d_in[1];
    const int*   dst  = (const int*)d_in[2];
    const float* W1_0 = (const float*)d_in[3];
    const float* b1_0 = (const float*)d_in[4];
    const float* W2_0 = (const float*)d_in[5];
    const float* b2_0 = (const float*)d_in[6];
    const float* g_0  = (const float*)d_in[7];
    const float* be_0 = (const float*)d_in[8];
    const float* W1st = (const float*)d_in[9];
    const float* b1st = (const float*)d_in[10];
    const float* W2st = (const float*)d_in[11];
    const float* b2st = (const float*)d_in[12];
    const float* gst  = (const float*)d_in[13];
    const float* best = (const float*)d_in[14];
    float* out = (float*)d_out;

    char* ws = (char*)d_ws;
    unsigned short* p  = (unsigned short*)ws;                    // NN*64 bf16
    unsigned short* Y  = p + (size_t)NN * 64;                    // NN*64 bf16
    unsigned short* zb = Y + (size_t)NN * 64;                    // NN*64 bf16
    unsigned* tmp = (unsigned*)(zb + (size_t)NN * 64);           // NB*CAP u32
    int* eidx   = (int*)(tmp + (size_t)NB * CAP);                // NE
    float* stats = (float*)(eidx + NE);                          // 512 floats
    int* gcount = (int*)(stats + 512);                           // NB (adjacent)
    int* off    = gcount + NB;                                   // NN+1

    // ---- CSR build: zero -> binA -> binB ----
    zero_kernel<<<3, 256, 0, stream>>>((int*)stats, 512 + NB);
    binA_kernel<<<(NE + CHUNK - 1) / CHUNK, 256, 0, stream>>>(src, dst, gcount, tmp);
    binB_kernel<<<NB, 256, 0, stream>>>(tmp, gcount, off, eidx);

    const int gemmblk   = (NN + 127) / 128;
    const int gatherblk = (NN * 8 + 255) / 256;
    const int normblk   = (NN * 8 + 255) / 256;

    float* gs0 = stats + 0 * 128;
    proj_kernel<128, false><<<gemmblk, 256, 0, stream>>>(
        h, W1_0, nullptr, nullptr, nullptr, nullptr, p);
    gather_kernel<<<gatherblk, 256, 0, stream>>>(p, off, eidx, b1_0, Y);
    mlp2_kernel<<<gemmblk, 256, 0, stream>>>(Y, W2_0, b2_0, zb, gs0, gs0 + 64);

    const float* gammas[4] = { g_0, gst + 0, gst + 64, gst + 128 };
    const float* betas[4]  = { be_0, best + 0, best + 64, best + 128 };

    for (int l = 0; l < 3; ++l) {
        float* gsp = stats + l * 128;
        float* gsc = stats + (l + 1) * 128;
        proj_kernel<64, true><<<gemmblk, 256, 0, stream>>>(
            zb, W1st + l * 4096, gsp, gsp + 64, gammas[l], betas[l], p);
        gather_kernel<<<gatherblk, 256, 0, stream>>>(p, off, eidx, b1st + l * 64, Y);
        mlp2_kernel<<<gemmblk, 256, 0, stream>>>(
            Y, W2st + l * 4096, b2st + l * 64, zb, gsc, gsc + 64);
    }

    float* gs3 = stats + 3 * 128;
    norm_kernel<<<normblk, 256, 0, stream>>>(zb, gs3, gs3 + 64, gammas[3], betas[3], out);
}

// Round 11
// 247.762 us; speedup vs baseline: 1.8715x; 1.0342x over previous
//
#include <hip/hip_runtime.h>
#include <hip/hip_bf16.h>

static constexpr int NN = 50000;
static constexpr int NE = 800000;
static constexpr float BN_EPS = 1e-5f;

static constexpr int NB  = 128;    // dst buckets
static constexpr int NPB = 391;    // nodes per bucket (128*391 = 50048 >= NN)
static constexpr int CAP = 8192;   // tmp slots per bucket (max bucket ~6600)
static constexpr int CHUNK = 2048;
static constexpr int SRNG = 12500; // src-range width (4 ranges: p slice 1.6MB < L2)

__device__ __forceinline__ float bflo(unsigned u) { return __uint_as_float(u << 16); }
__device__ __forceinline__ float bfhi(unsigned u) { return __uint_as_float(u & 0xffff0000u); }
__device__ __forceinline__ unsigned short f2bf(float f) {
    unsigned u = __float_as_uint(f);
    unsigned r = (u + 0x7fffu + ((u >> 16) & 1u)) >> 16;
    return (unsigned short)r;
}

// ===========================================================================
// zero: stats (512 f) + gcount (NB ints), contiguous
// ===========================================================================
__global__ __launch_bounds__(256) void zero_kernel(int* __restrict__ ptr, int n)
{
    int i = blockIdx.x * 256 + threadIdx.x;
    if (i < n) ptr[i] = 0;
}

// ===========================================================================
// binA: LDS-bin edges by dst bucket into fixed-cap bucket-major tmp (u32:
// (dst<<16)|src). gcount[b] accumulates bucket counts.
// ===========================================================================
__global__ __launch_bounds__(256) void binA_kernel(
    const int* __restrict__ src, const int* __restrict__ dst,
    int* __restrict__ gcount, unsigned* __restrict__ tmp)
{
    __shared__ unsigned stage[CHUNK];
    __shared__ int hist[NB], base[NB], gpos[NB];

    const int t = threadIdx.x;
    const int cb = blockIdx.x * CHUNK;
    const int total = min(CHUNK, NE - cb);

    if (t < NB) hist[t] = 0;
    __syncthreads();

    int mb[8], mslot[8];
    unsigned mv[8];
    #pragma unroll
    for (int k = 0; k < 8; ++k) {
        int e = cb + k * 256 + t;
        mb[k] = -1;
        if (e < NE) {
            int s = src[e];
            int d = dst[e];
            int b = d / NPB;
            mb[k] = b;
            mv[k] = ((unsigned)d << 16) | (unsigned)s;
            mslot[k] = atomicAdd(&hist[b], 1);
        }
    }
    __syncthreads();

    if (t < NB) base[t] = hist[t];
    __syncthreads();
    for (int ofs = 1; ofs < NB; ofs <<= 1) {
        int v = (t >= ofs && t < NB) ? base[t - ofs] : 0;
        __syncthreads();
        if (t < NB) base[t] += v;
        __syncthreads();
    }
    if (t < NB && hist[t] > 0)
        gpos[t] = t * CAP + atomicAdd(&gcount[t], hist[t]);
    __syncthreads();

    #pragma unroll
    for (int k = 0; k < 8; ++k) {
        if (mb[k] >= 0) {
            int b = mb[k];
            stage[(base[b] - hist[b]) + mslot[k]] = mv[k];
        }
    }
    __syncthreads();

    for (int i = t; i < total; i += 256) {
        unsigned v = stage[i];
        int b = (int)(v >> 16) / NPB;
        int pos = gpos[b] + (i - (base[b] - hist[b]));
        tmp[pos] = v;
    }
}

// ===========================================================================
// binB: one block per bucket. Per-(node,src-range) histogram + LDS scan ->
// global off + eidx with each node's edges ORDERED BY SRC RANGE (L2 locality
// for the gather: co-resident waves sweep ranges in loose lockstep).
// ===========================================================================
__global__ __launch_bounds__(256) void binB_kernel(
    const unsigned* __restrict__ tmp, const int* __restrict__ gcount,
    int* __restrict__ off, int* __restrict__ eidx)
{
    __shared__ int gb[NB];
    __shared__ int hist4[NPB * 4];
    __shared__ int hs[512];
    __shared__ int cur4[NPB * 4];
    __shared__ int base_s;

    const int t = threadIdx.x;
    const int b = blockIdx.x;
    const int n0 = b * NPB;
    const int n1 = min(n0 + NPB, NN);
    const int nnodes = n1 - n0;
    const int cnt = gcount[b];

    if (t < NB) gb[t] = gcount[t];
    for (int i = t; i < NPB * 4; i += 256) hist4[i] = 0;
    __syncthreads();
    // inclusive scan over bucket counts -> this bucket's global base
    for (int ofs = 1; ofs < NB; ofs <<= 1) {
        int v = (t >= ofs && t < NB) ? gb[t - ofs] : 0;
        __syncthreads();
        if (t < NB) gb[t] += v;
        __syncthreads();
    }
    if (t == 0) base_s = (b == 0) ? 0 : gb[b - 1];
    __syncthreads();
    const int base = base_s;

    const unsigned* tb = tmp + (size_t)b * CAP;
    for (int i = t; i < cnt; i += 256) {
        unsigned v = tb[i];
        int d = (int)(v >> 16);
        int s = (int)(v & 0xffffu);
        atomicAdd(&hist4[(d - n0) * 4 + s / SRNG], 1);
    }
    __syncthreads();
    // node totals, inclusive Hillis-Steele scan (padded to 512)
    {
        int n = t;
        hs[t] = (n < NPB) ? (hist4[n * 4] + hist4[n * 4 + 1] +
                             hist4[n * 4 + 2] + hist4[n * 4 + 3]) : 0;
        n = t + 256;
        hs[t + 256] = (n < NPB) ? (hist4[n * 4] + hist4[n * 4 + 1] +
                                   hist4[n * 4 + 2] + hist4[n * 4 + 3]) : 0;
    }
    __syncthreads();
    for (int ofs = 1; ofs < 512; ofs <<= 1) {
        int a0 = (t >= ofs) ? hs[t - ofs] : 0;
        int a1 = hs[t + 256 - ofs];
        __syncthreads();
        hs[t] += a0;
        hs[t + 256] += a1;
        __syncthreads();
    }
    // off + per-range cursors (exclusive = inclusive - total)
    for (int n = t; n < nnodes; n += 256) {
        int h0 = hist4[n * 4], h1 = hist4[n * 4 + 1], h2 = hist4[n * 4 + 2];
        int tot = h0 + h1 + h2 + hist4[n * 4 + 3];
        int c = base + hs[n] - tot;
        off[n0 + n] = c;
        cur4[n * 4 + 0] = c; c += h0;
        cur4[n * 4 + 1] = c; c += h1;
        cur4[n * 4 + 2] = c; c += h2;
        cur4[n * 4 + 3] = c;
    }
    if (b == NB - 1 && t == 0) off[NN] = base + cnt;
    __syncthreads();
    // scatter into this bucket's private eidx window, src-range ordered
    for (int i = t; i < cnt; i += 256) {
        unsigned v = tb[i];
        int d = (int)(v >> 16);
        int s = (int)(v & 0xffffu);
        int pos = atomicAdd(&cur4[(d - n0) * 4 + s / SRNG], 1);
        eidx[pos] = s;
    }
}

// ===========================================================================
// proj: p(bf16) = act(hin) @ W1.
//   NORM=false: hin fp32 [NN][D] (layer 0 input)
//   NORM=true : hin bf16 [NN][64] (zb), apply BN(scale/shift)+relu on load
// 128 rows/block, tile 4x8.
// ===========================================================================
template<int D, bool NORM>
__global__ __launch_bounds__(256) void proj_kernel(
    const void* __restrict__ hin_, const float* __restrict__ W1,
    const float* __restrict__ gsum, const float* __restrict__ gsq,
    const float* __restrict__ gamma, const float* __restrict__ beta,
    unsigned short* __restrict__ p)
{
    constexpr int RPB = 128;
    __shared__ float XsT[64][132];
    __shared__ float Ws[64][64];
    __shared__ float scs[64], shs[64];

    const int t = threadIdx.x;
    const int rowbase = blockIdx.x * RPB;

    if (NORM) {
        if (t < 64) {
            const float invn = 1.f / (float)NN;
            float mean = gsum[t] * invn;
            float var  = gsq[t] * invn - mean * mean;
            float sc   = gamma[t] * rsqrtf(var + BN_EPS);
            scs[t] = sc;
            shs[t] = beta[t] - mean * sc;
        }
        __syncthreads();
    }

    const int tc = t & 7;
    const int tr = t >> 3;
    const int c0 = tc * 8;
    const int r0 = tr * 4;

    float acc[4][8];
    #pragma unroll
    for (int i = 0; i < 4; ++i)
        #pragma unroll
        for (int j = 0; j < 8; ++j) acc[i][j] = 0.f;

    for (int kc = 0; kc < D; kc += 64) {
        if (kc) __syncthreads();
        {
            const float4* wg = reinterpret_cast<const float4*>(W1 + (size_t)kc * 64);
            float4* wl = reinterpret_cast<float4*>(&Ws[0][0]);
            for (int i = t; i < 64 * 16; i += 256) wl[i] = wg[i];
        }
        if constexpr (NORM) {
            const uint4* hb = reinterpret_cast<const uint4*>(hin_);
            int rr = t & 31, q = t >> 5;
            for (int i = 0; i < RPB; i += 32) {
                int r = i + rr;
                int gr = rowbase + r;
                uint4 v = make_uint4(0u, 0u, 0u, 0u);
                if (gr < NN) v = hb[gr * 8 + q];
                int c = q * 8;
                float f0 = bflo(v.x), f1 = bfhi(v.x), f2 = bflo(v.y), f3 = bfhi(v.y);
                float f4 = bflo(v.z), f5 = bfhi(v.z), f6 = bflo(v.w), f7 = bfhi(v.w);
                XsT[c + 0][r] = fmaxf(f0 * scs[c + 0] + shs[c + 0], 0.f);
                XsT[c + 1][r] = fmaxf(f1 * scs[c + 1] + shs[c + 1], 0.f);
                XsT[c + 2][r] = fmaxf(f2 * scs[c + 2] + shs[c + 2], 0.f);
                XsT[c + 3][r] = fmaxf(f3 * scs[c + 3] + shs[c + 3], 0.f);
                XsT[c + 4][r] = fmaxf(f4 * scs[c + 4] + shs[c + 4], 0.f);
                XsT[c + 5][r] = fmaxf(f5 * scs[c + 5] + shs[c + 5], 0.f);
                XsT[c + 6][r] = fmaxf(f6 * scs[c + 6] + shs[c + 6], 0.f);
                XsT[c + 7][r] = fmaxf(f7 * scs[c + 7] + shs[c + 7], 0.f);
            }
        } else {
            const float* hin = reinterpret_cast<const float*>(hin_);
            int rr = t & 15, q = t >> 4;
            for (int i = 0; i < RPB; i += 16) {
                int r = i + rr;
                int gr = rowbase + r;
                float4 v = make_float4(0.f, 0.f, 0.f, 0.f);
                if (gr < NN)
                    v = reinterpret_cast<const float4*>(hin + (size_t)gr * D + kc)[q];
                XsT[q * 4 + 0][r] = v.x;
                XsT[q * 4 + 1][r] = v.y;
                XsT[q * 4 + 2][r] = v.z;
                XsT[q * 4 + 3][r] = v.w;
            }
        }
        __syncthreads();

        for (int k = 0; k < 64; ++k) {
            float4 xa = *reinterpret_cast<const float4*>(&XsT[k][r0]);
            float4 wa = *reinterpret_cast<const float4*>(&Ws[k][c0]);
            float4 wb = *reinterpret_cast<const float4*>(&Ws[k][c0 + 4]);
            float x[4] = { xa.x, xa.y, xa.z, xa.w };
            float w[8] = { wa.x, wa.y, wa.z, wa.w, wb.x, wb.y, wb.z, wb.w };
            #pragma unroll
            for (int i = 0; i < 4; ++i)
                #pragma unroll
                for (int j = 0; j < 8; ++j) acc[i][j] += x[i] * w[j];
        }
    }

    #pragma unroll
    for (int i = 0; i < 4; ++i) {
        int gr = rowbase + r0 + i;
        if (gr < NN) {
            uint4 u;
            u.x = (unsigned)f2bf(acc[i][0]) | ((unsigned)f2bf(acc[i][1]) << 16);
            u.y = (unsigned)f2bf(acc[i][2]) | ((unsigned)f2bf(acc[i][3]) << 16);
            u.z = (unsigned)f2bf(acc[i][4]) | ((unsigned)f2bf(acc[i][5]) << 16);
            u.w = (unsigned)f2bf(acc[i][6]) | ((unsigned)f2bf(acc[i][7]) << 16);
            *reinterpret_cast<uint4*>(p + (size_t)gr * 64 + c0) = u;
        }
    }
}

// ===========================================================================
// gather: Y[i] = relu(p[i] + sum_{j in N(i)} p[j] + b1)   (bf16 in/out)
// ===========================================================================
__global__ __launch_bounds__(256) void gather_kernel(
    const unsigned short* __restrict__ p, const int* __restrict__ off,
    const int* __restrict__ eidx, const float* __restrict__ b1,
    unsigned short* __restrict__ Y)
{
    int gid = blockIdx.x * 256 + threadIdx.x;
    if (gid >= NN * 8) return;
    int row = gid >> 3;
    int q = gid & 7;

    const uint4* pb = reinterpret_cast<const uint4*>(p);
    uint4 u = pb[row * 8 + q];
    float a0 = bflo(u.x), a1 = bfhi(u.x), a2 = bflo(u.y), a3 = bfhi(u.y);
    float a4 = bflo(u.z), a5 = bfhi(u.z), a6 = bflo(u.w), a7 = bfhi(u.w);

    int e = off[row];
    const int end = off[row + 1];
    for (; e + 4 <= end; e += 4) {
        int s0 = eidx[e + 0], s1 = eidx[e + 1];
        int s2 = eidx[e + 2], s3 = eidx[e + 3];
        uint4 v0 = pb[s0 * 8 + q];
        uint4 v1 = pb[s1 * 8 + q];
        uint4 v2 = pb[s2 * 8 + q];
        uint4 v3 = pb[s3 * 8 + q];
        a0 += (bflo(v0.x) + bflo(v1.x)) + (bflo(v2.x) + bflo(v3.x));
        a1 += (bfhi(v0.x) + bfhi(v1.x)) + (bfhi(v2.x) + bfhi(v3.x));
        a2 += (bflo(v0.y) + bflo(v1.y)) + (bflo(v2.y) + bflo(v3.y));
        a3 += (bfhi(v0.y) + bfhi(v1.y)) + (bfhi(v2.y) + bfhi(v3.y));
        a4 += (bflo(v0.z) + bflo(v1.z)) + (bflo(v2.z) + bflo(v3.z));
        a5 += (bfhi(v0.z) + bfhi(v1.z)) + (bfhi(v2.z) + bfhi(v3.z));
        a6 += (bflo(v0.w) + bflo(v1.w)) + (bflo(v2.w) + bflo(v3.w));
        a7 += (bfhi(v0.w) + bfhi(v1.w)) + (bfhi(v2.w) + bfhi(v3.w));
    }
    for (; e < end; ++e) {
        uint4 v = pb[eidx[e] * 8 + q];
        a0 += bflo(v.x); a1 += bfhi(v.x); a2 += bflo(v.y); a3 += bfhi(v.y);
        a4 += bflo(v.z); a5 += bfhi(v.z); a6 += bflo(v.w); a7 += bfhi(v.w);
    }

    float4 blo = reinterpret_cast<const float4*>(b1)[q * 2];
    float4 bhi = reinterpret_cast<const float4*>(b1)[q * 2 + 1];
    a0 = fmaxf(a0 + blo.x, 0.f); a1 = fmaxf(a1 + blo.y, 0.f);
    a2 = fmaxf(a2 + blo.z, 0.f); a3 = fmaxf(a3 + blo.w, 0.f);
    a4 = fmaxf(a4 + bhi.x, 0.f); a5 = fmaxf(a5 + bhi.y, 0.f);
    a6 = fmaxf(a6 + bhi.z, 0.f); a7 = fmaxf(a7 + bhi.w, 0.f);

    uint4 o;
    o.x = (unsigned)f2bf(a0) | ((unsigned)f2bf(a1) << 16);
    o.y = (unsigned)f2bf(a2) | ((unsigned)f2bf(a3) << 16);
    o.z = (unsigned)f2bf(a4) | ((unsigned)f2bf(a5) << 16);
    o.w = (unsigned)f2bf(a6) | ((unsigned)f2bf(a7) << 16);
    reinterpret_cast<uint4*>(Y)[row * 8 + q] = o;
}

// ===========================================================================
// mlp2: z = Y @ W2 + b2 (Y bf16 -> fp32 math), store z as bf16, BN stats fp32.
// ===========================================================================
__global__ __launch_bounds__(256) void mlp2_kernel(
    const unsigned short* __restrict__ Y, const float* __restrict__ W2,
    const float* __restrict__ b2, unsigned short* __restrict__ zb,
    float* __restrict__ gsum, float* __restrict__ gsq)
{
    constexpr int RPB = 128;
    __shared__ float XsT[64][132];
    __shared__ float Ws[64][64];
    __shared__ float b2s[64], lsum[64], lsq[64];

    const int t = threadIdx.x;
    const int rowbase = blockIdx.x * RPB;

    if (t < 64) { b2s[t] = b2[t]; lsum[t] = 0.f; lsq[t] = 0.f; }

    {
        const float4* wg = reinterpret_cast<const float4*>(W2);
        float4* wl = reinterpret_cast<float4*>(&Ws[0][0]);
        for (int i = t; i < 64 * 16; i += 256) wl[i] = wg[i];
    }
    {
        const uint4* yb = reinterpret_cast<const uint4*>(Y);
        int rr = t & 31, qq = t >> 5;
        for (int i = 0; i < RPB; i += 32) {
            int r = i + rr;
            int gr = rowbase + r;
            uint4 v = make_uint4(0u, 0u, 0u, 0u);
            if (gr < NN) v = yb[gr * 8 + qq];
            int c = qq * 8;
            XsT[c + 0][r] = bflo(v.x); XsT[c + 1][r] = bfhi(v.x);
            XsT[c + 2][r] = bflo(v.y); XsT[c + 3][r] = bfhi(v.y);
            XsT[c + 4][r] = bflo(v.z); XsT[c + 5][r] = bfhi(v.z);
            XsT[c + 6][r] = bflo(v.w); XsT[c + 7][r] = bfhi(v.w);
        }
    }
    __syncthreads();

    const int tc = t & 7;
    const int tr = t >> 3;
    const int c0 = tc * 8;
    const int r0 = tr * 4;

    float acc[4][8];
    #pragma unroll
    for (int i = 0; i < 4; ++i)
        #pragma unroll
        for (int j = 0; j < 8; ++j) acc[i][j] = 0.f;

    for (int k = 0; k < 64; ++k) {
        float4 xa = *reinterpret_cast<const float4*>(&XsT[k][r0]);
        float4 wa = *reinterpret_cast<const float4*>(&Ws[k][c0]);
        float4 wb = *reinterpret_cast<const float4*>(&Ws[k][c0 + 4]);
        float x[4] = { xa.x, xa.y, xa.z, xa.w };
        float w[8] = { wa.x, wa.y, wa.z, wa.w, wb.x, wb.y, wb.z, wb.w };
        #pragma unroll
        for (int i = 0; i < 4; ++i)
            #pragma unroll
            for (int j = 0; j < 8; ++j) acc[i][j] += x[i] * w[j];
    }

    float s[8], sq[8];
    #pragma unroll
    for (int j = 0; j < 8; ++j) { s[j] = 0.f; sq[j] = 0.f; }

    #pragma unroll
    for (int i = 0; i < 4; ++i) {
        int gr = rowbase + r0 + i;
        if (gr < NN) {
            float zv[8];
            #pragma unroll
            for (int j = 0; j < 8; ++j) {
                zv[j] = acc[i][j] + b2s[c0 + j];
                s[j] += zv[j];
                sq[j] += zv[j] * zv[j];
            }
            uint4 o;
            o.x = (unsigned)f2bf(zv[0]) | ((unsigned)f2bf(zv[1]) << 16);
            o.y = (unsigned)f2bf(zv[2]) | ((unsigned)f2bf(zv[3]) << 16);
            o.z = (unsigned)f2bf(zv[4]) | ((unsigned)f2bf(zv[5]) << 16);
            o.w = (unsigned)f2bf(zv[6]) | ((unsigned)f2bf(zv[7]) << 16);
            *reinterpret_cast<uint4*>(zb + (size_t)gr * 64 + c0) = o;
        }
    }

    #pragma unroll
    for (int j = 0; j < 8; ++j) {
        s[j]  += __shfl_xor(s[j], 8);
        s[j]  += __shfl_xor(s[j], 16);
        s[j]  += __shfl_xor(s[j], 32);
        sq[j] += __shfl_xor(sq[j], 8);
        sq[j] += __shfl_xor(sq[j], 16);
        sq[j] += __shfl_xor(sq[j], 32);
    }
    if ((t & 56) == 0) {
        #pragma unroll
        for (int j = 0; j < 8; ++j) {
            atomicAdd(&lsum[c0 + j], s[j]);
            atomicAdd(&lsq[c0 + j], sq[j]);
        }
    }
    __syncthreads();
    if (t < 64) {
        atomicAdd(&gsum[t], lsum[t]);
        atomicAdd(&gsq[t], lsq[t]);
    }
}

// ===========================================================================
// final norm: out(fp32) = relu(zb*scale+shift), zb bf16
// ===========================================================================
__global__ __launch_bounds__(256) void norm_kernel(
    const unsigned short* __restrict__ zb,
    const float* __restrict__ gsum, const float* __restrict__ gsq,
    const float* __restrict__ gamma, const float* __restrict__ beta,
    float* __restrict__ out)
{
    __shared__ float sc[64], sh[64];
    int t = threadIdx.x;
    if (t < 64) {
        const float invn = 1.f / (float)NN;
        float mean = gsum[t] * invn;
        float var  = gsq[t] * invn - mean * mean;
        float s    = gamma[t] * rsqrtf(var + BN_EPS);
        sc[t] = s;
        sh[t] = beta[t] - mean * s;
    }
    __syncthreads();
    int idx = blockIdx.x * 256 + t;
    if (idx >= NN * 8) return;
    int row = idx >> 3;
    int q = idx & 7;
    int c = q * 8;
    uint4 v = reinterpret_cast<const uint4*>(zb)[idx];
    float f0 = bflo(v.x), f1 = bfhi(v.x), f2 = bflo(v.y), f3 = bfhi(v.y);
    float f4 = bflo(v.z), f5 = bfhi(v.z), f6 = bflo(v.w), f7 = bfhi(v.w);
    float4 lo, hi;
    lo.x = fmaxf(f0 * sc[c + 0] + sh[c + 0], 0.f);
    lo.y = fmaxf(f1 * sc[c + 1] + sh[c + 1], 0.f);
    lo.z = fmaxf(f2 * sc[c + 2] + sh[c + 2], 0.f);
    lo.w = fmaxf(f3 * sc[c + 3] + sh[c + 3], 0.f);
    hi.x = fmaxf(f4 * sc[c + 4] + sh[c + 4], 0.f);
    hi.y = fmaxf(f5 * sc[c + 5] + sh[c + 5], 0.f);
    hi.z = fmaxf(f6 * sc[c + 6] + sh[c + 6], 0.f);
    hi.w = fmaxf(f7 * sc[c + 7] + sh[c + 7], 0.f);
    float* o = out + (size_t)row * 64 + c;
    *reinterpret_cast<float4*>(o) = lo;
    *reinterpret_cast<float4*>(o + 4) = hi;
}

// ===========================================================================
extern "C" void kernel_launch(void* const* d_in, const int* in_sizes, int n_in,
                              void* d_out, int out_size, void* d_ws, size_t ws_size,
                              hipStream_t stream)
{
    const float* h    = (const float*)d_in[0];
    const int*   src  = (const int*)d_in[1];
    const int*   dst  = (const int*)d_in[2];
    const float* W1_0 = (const float*)d_in[3];
    const float* b1_0 = (const float*)d_in[4];
    const float* W2_0 = (const float*)d_in[5];
    const float* b2_0 = (const float*)d_in[6];
    const float* g_0  = (const float*)d_in[7];
    const float* be_0 = (const float*)d_in[8];
    const float* W1st = (const float*)d_in[9];
    const float* b1st = (const float*)d_in[10];
    const float* W2st = (const float*)d_in[11];
    const float* b2st = (const float*)d_in[12];
    const float* gst  = (const float*)d_in[13];
    const float* best = (const float*)d_in[14];
    float* out = (float*)d_out;

    char* ws = (char*)d_ws;
    unsigned short* p  = (unsigned short*)ws;                    // NN*64 bf16
    unsigned short* Y  = p + (size_t)NN * 64;                    // NN*64 bf16
    unsigned short* zb = Y + (size_t)NN * 64;                    // NN*64 bf16
    unsigned* tmp = (unsigned*)(zb + (size_t)NN * 64);           // NB*CAP u32
    int* eidx   = (int*)(tmp + (size_t)NB * CAP);                // NE
    float* stats = (float*)(eidx + NE);                          // 512 floats
    int* gcount = (int*)(stats + 512);                           // NB (adjacent)
    int* off    = gcount + NB;                                   // NN+1

    // ---- CSR build: zero -> binA -> binB ----
    zero_kernel<<<3, 256, 0, stream>>>((int*)stats, 512 + NB);
    binA_kernel<<<(NE + CHUNK - 1) / CHUNK, 256, 0, stream>>>(src, dst, gcount, tmp);
    binB_kernel<<<NB, 256, 0, stream>>>(tmp, gcount, off, eidx);

    const int gemmblk   = (NN + 127) / 128;
    const int gatherblk = (NN * 8 + 255) / 256;
    const int normblk   = (NN * 8 + 255) / 256;

    float* gs0 = stats + 0 * 128;
    proj_kernel<128, false><<<gemmblk, 256, 0, stream>>>(
        h, W1_0, nullptr, nullptr, nullptr, nullptr, p);
    gather_kernel<<<gatherblk, 256, 0, stream>>>(p, off, eidx, b1_0, Y);
    mlp2_kernel<<<gemmblk, 256, 0, stream>>>(Y, W2_0, b2_0, zb, gs0, gs0 + 64);

    const float* gammas[4] = { g_0, gst + 0, gst + 64, gst + 128 };
    const float* betas[4]  = { be_0, best + 0, best + 64, best + 128 };

    for (int l = 0; l < 3; ++l) {
        float* gsp = stats + l * 128;
        float* gsc = stats + (l + 1) * 128;
        proj_kernel<64, true><<<gemmblk, 256, 0, stream>>>(
            zb, W1st + l * 4096, gsp, gsp + 64, gammas[l], betas[l], p);
        gather_kernel<<<gatherblk, 256, 0, stream>>>(p, off, eidx, b1st + l * 64, Y);
        mlp2_kernel<<<gemmblk, 256, 0, stream>>>(
            Y, W2st + l * 4096, b2st + l * 64, zb, gsc, gsc + 64);
    }

    float* gs3 = stats + 3 * 128;
    norm_kernel<<<normblk, 256, 0, stream>>>(zb, gs3, gs3 + 64, gammas[3], betas[3], out);
}